// Round 4
// baseline (165.368 us; speedup 1.0000x reference)
//
#include <hip/hip_runtime.h>
#include <hip/hip_bf16.h>

#define NNODES 16384

typedef unsigned short u16;
typedef unsigned int   u32;
typedef __attribute__((ext_vector_type(8))) short bf16x8;
typedef __attribute__((ext_vector_type(4))) float f32x4;

__device__ __forceinline__ float bfl(u32 u) { return __uint_as_float(u << 16); }
__device__ __forceinline__ float bfh(u32 u) { return __uint_as_float(u & 0xffff0000u); }
__device__ __forceinline__ u16 f2b(float f) {
    u32 u = __float_as_uint(f);
    return (u16)((u + 0x7fffu + ((u >> 16) & 1u)) >> 16);
}

// ---------------------------------------------------------------------------
// Weight cast+transpose: six [128][128] f32 row-major -> bf16 [col][k].
// order: Wk, Wq, Wv, W1a, W1b, W2
// ---------------------------------------------------------------------------
__global__ __launch_bounds__(256) void wcast_kernel(
    const float* __restrict__ Wk, const float* __restrict__ Wq,
    const float* __restrict__ Wv, const float* __restrict__ W1,
    const float* __restrict__ W2, u16* __restrict__ Wts)
{
    int mat = blockIdx.x;
    const float* src = (mat == 0) ? Wk : (mat == 1) ? Wq : (mat == 2) ? Wv
                     : (mat == 3) ? W1 : (mat == 4) ? (W1 + 128 * 128) : W2;
    u16* dst = Wts + (size_t)mat * 16384;
    int t = threadIdx.x;
    #pragma unroll
    for (int i = 0; i < 64; i++) {
        int idx = i * 256 + t;
        int k = idx >> 7, c = idx & 127;
        dst[c * 128 + k] = f2b(src[idx]);
    }
}

// ---------------------------------------------------------------------------
// qbias[c] = bq[c] + btq[c] + enc(t) @ Wtq[:,c]
// ---------------------------------------------------------------------------
__global__ void prep_kernel(
    const float* __restrict__ t, const float* __restrict__ bq,
    const float* __restrict__ btq, const float* __restrict__ Wtq,
    const float* __restrict__ w0, const float* __restrict__ b0,
    const float* __restrict__ Wt, const float* __restrict__ Bt,
    float* __restrict__ qbias)
{
    int c = threadIdx.x;
    if (c < 128) {
        float tv = t[0];
        float s = bq[c] + btq[c];
        float e0 = w0[0] * tv + b0[0];
        s += e0 * Wtq[c];
        for (int k = 1; k < 64; k++) {
            float e = __sinf(tv * Wt[k - 1] + Bt[k - 1]);
            s += e * Wtq[k * 128 + c];
        }
        qbias[c] = s;
    }
}

// ---------------------------------------------------------------------------
// Shared MFMA core: 128x128 tile, K=128, 4 waves, 16x16x32 bf16 MFMA.
// As/Ws: bf16 LDS, [row][k] layout, XOR-swizzled (idx16 ^= (row&7)<<3).
// A = f32 global row-major (cast inline); Wt = bf16 global [col][k].
// ---------------------------------------------------------------------------
__device__ __forceinline__ void mfma_core(
    const float* __restrict__ A, const u16* __restrict__ Wt,
    u16* As, u16* Ws, int rb, int t, f32x4 acc[2][8])
{
    u32* As32 = (u32*)As;
    u32* Ws32 = (u32*)Ws;
    const float2* Ap = (const float2*)(A + (size_t)rb * 128);
    const u32*   Wp = (const u32*)Wt;
    #pragma unroll
    for (int i = 0; i < 32; i++) {
        int idx2 = i * 256 + t;          // pair index
        int r = idx2 >> 6, k2 = idx2 & 63;
        float2 v = Ap[idx2];
        As32[(r * 64 + k2) ^ ((r & 7) << 2)] = (u32)f2b(v.x) | ((u32)f2b(v.y) << 16);
    }
    #pragma unroll
    for (int i = 0; i < 32; i++) {
        int idx2 = i * 256 + t;
        int c = idx2 >> 6, k2 = idx2 & 63;
        Ws32[(c * 64 + k2) ^ ((c & 7) << 2)] = Wp[idx2];
    }
    __syncthreads();

    int wid = t >> 6, lane = t & 63;
    int l15 = lane & 15, lg = lane >> 4;
    int mb = wid * 32;
    int xo = (l15 & 7) << 3;             // u16-index XOR for this lane's rows/cols

    #pragma unroll
    for (int mi = 0; mi < 2; mi++)
        #pragma unroll
        for (int nt = 0; nt < 8; nt++)
            acc[mi][nt] = (f32x4){0.f, 0.f, 0.f, 0.f};

    #pragma unroll
    for (int ks = 0; ks < 4; ks++) {
        int kq = ks * 32 + lg * 8;
        bf16x8 a0 = *(bf16x8*)&As[((mb + l15) * 128 + kq) ^ xo];
        bf16x8 a1 = *(bf16x8*)&As[((mb + 16 + l15) * 128 + kq) ^ xo];
        #pragma unroll
        for (int nt = 0; nt < 8; nt++) {
            bf16x8 b = *(bf16x8*)&Ws[((nt * 16 + l15) * 128 + kq) ^ xo];
            acc[0][nt] = __builtin_amdgcn_mfma_f32_16x16x32_bf16(a0, b, acc[0][nt], 0, 0, 0);
            acc[1][nt] = __builtin_amdgcn_mfma_f32_16x16x32_bf16(a1, b, acc[1][nt], 0, 0, 0);
        }
    }
}

// ---------------------------------------------------------------------------
// Fused 4-matrix MFMA GEMM over x. blockIdx.y = mat:
//   0: Kb (bf16)  1: Qtab (f32)  2: Vb (bf16)  3: Ptab (f32)
// ---------------------------------------------------------------------------
__global__ __launch_bounds__(256) void gemm4m(
    const float* __restrict__ x, const u16* __restrict__ Wts,
    const float* __restrict__ bk, const float* __restrict__ qbias,
    const float* __restrict__ bv, const float* __restrict__ b1,
    u16* __restrict__ Kb, float* __restrict__ Qtab,
    u16* __restrict__ Vb, float* __restrict__ Ptab)
{
    __shared__ u16 As[128 * 128];
    __shared__ u16 Ws[128 * 128];
    int t = threadIdx.x;
    int rb = blockIdx.x * 128;
    int mat = blockIdx.y;
    const u16* Wt = Wts + (size_t)mat * 16384;
    const float* bias = (mat == 0) ? bk : (mat == 1) ? qbias : (mat == 2) ? bv : b1;

    f32x4 acc[2][8];
    mfma_core(x, Wt, As, Ws, rb, t, acc);

    int wid = t >> 6, lane = t & 63;
    int l15 = lane & 15, lg = lane >> 4;
    int mb = wid * 32;
    #pragma unroll
    for (int mi = 0; mi < 2; mi++) {
        #pragma unroll
        for (int nt = 0; nt < 8; nt++) {
            int c = nt * 16 + l15;
            float bvv = bias[c];
            #pragma unroll
            for (int j = 0; j < 4; j++) {
                size_t row = rb + mb + mi * 16 + lg * 4 + j;
                float v = acc[mi][nt][j] + bvv;
                if (mat == 0)      Kb[row * 128 + c] = f2b(v);
                else if (mat == 1) Qtab[row * 128 + c] = v;
                else if (mat == 2) Vb[row * 128 + c] = f2b(v);
                else               Ptab[row * 128 + c] = v;
            }
        }
    }
}

// ---------------------------------------------------------------------------
// Generic single MFMA GEMM: C = A@Wt (+bias) (+addsrc) (relu), f32 out.
// ---------------------------------------------------------------------------
__global__ __launch_bounds__(256) void gemm_m(
    const float* __restrict__ A, const u16* __restrict__ Wt,
    const float* __restrict__ bias, const float* __restrict__ addsrc,
    float* __restrict__ Cf, int relu)
{
    __shared__ u16 As[128 * 128];
    __shared__ u16 Ws[128 * 128];
    int t = threadIdx.x;
    int rb = blockIdx.x * 128;

    f32x4 acc[2][8];
    mfma_core(A, Wt, As, Ws, rb, t, acc);

    int wid = t >> 6, lane = t & 63;
    int l15 = lane & 15, lg = lane >> 4;
    int mb = wid * 32;
    #pragma unroll
    for (int mi = 0; mi < 2; mi++) {
        #pragma unroll
        for (int nt = 0; nt < 8; nt++) {
            int c = nt * 16 + l15;
            float bvv = bias ? bias[c] : 0.f;
            #pragma unroll
            for (int j = 0; j < 4; j++) {
                size_t row = rb + mb + mi * 16 + lg * 4 + j;
                float v = acc[mi][nt][j] + bvv;
                if (addsrc) v += addsrc[row * 128 + c];
                if (relu)   v = fmaxf(v, 0.f);
                Cf[row * 128 + c] = v;
            }
        }
    }
}

// ---------------------------------------------------------------------------
// G[n][h*64+k] = sum_{d<16} Qtab[n][h*16+d] * Wtk[k][h*16+d]   (bf16 out)
// ---------------------------------------------------------------------------
__global__ __launch_bounds__(256) void gcalc_kernel(
    const float* __restrict__ Qtab, const float* __restrict__ Wtk,
    u16* __restrict__ Gb)
{
    int t = blockIdx.x * 256 + threadIdx.x;
    int n = t >> 3, h = t & 7;
    float q[16];
    const float4* qp = (const float4*)(Qtab + (size_t)n * 128 + h * 16);
    #pragma unroll
    for (int i = 0; i < 4; i++) {
        float4 v = qp[i];
        q[4 * i] = v.x; q[4 * i + 1] = v.y; q[4 * i + 2] = v.z; q[4 * i + 3] = v.w;
    }
    u32 out[16];
    #pragma unroll
    for (int k4 = 0; k4 < 16; k4++) {
        float s[4];
        #pragma unroll
        for (int j = 0; j < 4; j++) {
            const float* wp = Wtk + (size_t)(4 * k4 + j) * 128 + h * 16;
            float a = 0.f;
            #pragma unroll
            for (int d = 0; d < 16; d++) a += q[d] * wp[d];
            s[j] = a;
        }
        out[2 * k4]     = (u32)f2b(s[0]) | ((u32)f2b(s[1]) << 16);
        out[2 * k4 + 1] = (u32)f2b(s[2]) | ((u32)f2b(s[3]) << 16);
    }
    int4* dst = (int4*)(Gb + (size_t)n * 512 + h * 64);
    const int4* src = (const int4*)out;
    #pragma unroll
    for (int i = 0; i < 4; i++) dst[i] = src[i];
}

// ---------------------------------------------------------------------------
// Attention: one wave per node, 4 waves/block, wave-private LDS (no barriers).
// ---------------------------------------------------------------------------
__global__ __launch_bounds__(256, 4) void attn_kernel(
    const int*   __restrict__ neighbors, const float* __restrict__ times,
    const float* __restrict__ tptr,
    const u16* __restrict__ Kb, const float* __restrict__ Qtab,
    const u16* __restrict__ Vb, const u16* __restrict__ Gb,
    const float* __restrict__ btk,  const float* __restrict__ Wtv,
    const float* __restrict__ btv,
    const float* __restrict__ w0,   const float* __restrict__ b0,
    const float* __restrict__ Wt,   const float* __restrict__ Bt,
    float* __restrict__ hbuf)
{
    __shared__ u16   enc[4][32][66];
    __shared__ float gbf[4][8][68];
    __shared__ float qbuf[4][128];
    __shared__ float attnb[4][8][33];
    __shared__ float ewb[4][8][65];
    __shared__ int   nbb[4][32];
    __shared__ float cb_[4][8];

    int t = threadIdx.x;
    int wid = t >> 6, lane = t & 63;
    int n = blockIdx.x * 4 + wid;
    float t0 = tptr[0];

    qbuf[wid][lane]      = Qtab[(size_t)n * 128 + lane];
    qbuf[wid][lane + 64] = Qtab[(size_t)n * 128 + 64 + lane];

    int m = lane & 31, h2 = lane >> 5;
    if (lane < 32) nbb[wid][lane] = neighbors[n * 32 + lane];
    float tm = times[n * 32 + m];
    bool valid = (tm <= t0);

    u32 vpre[32];
    #pragma unroll
    for (int mm = 0; mm < 32; mm++) {
        int nbm = nbb[wid][mm];
        vpre[mm] = *(const u32*)(Vb + (size_t)nbm * 128 + 2 * lane);
    }

    {
        int4 g4 = *(const int4*)(Gb + (size_t)n * 512 + 8 * lane);
        const u32* gw = (const u32*)&g4;
        #pragma unroll
        for (int i = 0; i < 4; i++) {
            int j = 8 * lane + 2 * i;
            gbf[wid][j >> 6][j & 63]       = bfl(gw[i]);
            gbf[wid][j >> 6][(j & 63) + 1] = bfh(gw[i]);
        }
    }

    float W0 = w0[0], B0 = b0[0];
    int kbase = 32 * h2;
    #pragma unroll
    for (int i = 0; i < 16; i++) {
        int k0 = kbase + 2 * i;
        float v0 = (k0 == 0) ? (W0 * tm + B0) : __sinf(tm * Wt[k0 - 1] + Bt[k0 - 1]);
        float v1 = __sinf(tm * Wt[k0] + Bt[k0]);
        *(u32*)&enc[wid][m][k0] = (u32)f2b(v0) | ((u32)f2b(v1) << 16);
    }

    if (lane < 8) {
        float s = 0.f;
        #pragma unroll
        for (int d = 0; d < 16; d++)
            s += qbuf[wid][lane * 16 + d] * btk[lane * 16 + d];
        cb_[wid][lane] = s;
    }

    float acc[4] = {0, 0, 0, 0};
    int nb = nbb[wid][m];
    const int4* Kr = (const int4*)(Kb + (size_t)nb * 128 + h2 * 64);
    #pragma unroll
    for (int j = 0; j < 8; j++) {
        int4 kk = Kr[j];
        int hh = j >> 1, d0 = (j & 1) * 8;
        const float* qp = &qbuf[wid][(4 * h2 + hh) * 16 + d0];
        acc[hh] += bfl(kk.x) * qp[0] + bfh(kk.x) * qp[1]
                 + bfl(kk.y) * qp[2] + bfh(kk.y) * qp[3]
                 + bfl(kk.z) * qp[4] + bfh(kk.z) * qp[5]
                 + bfl(kk.w) * qp[6] + bfh(kk.w) * qp[7];
    }
    #pragma unroll 4
    for (int c = 0; c < 16; c++) {
        u32 eA = *(const u32*)&enc[wid][m][4 * c];
        u32 eB = *(const u32*)&enc[wid][m][4 * c + 2];
        float e0 = bfl(eA), e1 = bfh(eA), e2 = bfl(eB), e3 = bfh(eB);
        #pragma unroll
        for (int hh = 0; hh < 4; hh++) {
            float4 g4 = *(const float4*)&gbf[wid][4 * h2 + hh][4 * c];
            acc[hh] += e0 * g4.x + e1 * g4.y + e2 * g4.z + e3 * g4.w;
        }
    }

    unsigned long long bal = __ballot(valid);
    bool anyv = (bal != 0ull);

    #pragma unroll
    for (int hh = 0; hh < 4; hh++) {
        float sc = valid ? 0.25f * (acc[hh] + cb_[wid][4 * h2 + hh]) : -1e9f;
        float mx = sc;
        for (int off = 16; off > 0; off >>= 1)
            mx = fmaxf(mx, __shfl_xor(mx, off));
        float p = __expf(sc - mx);
        float s = p;
        for (int off = 16; off > 0; off >>= 1)
            s += __shfl_xor(s, off);
        attnb[wid][4 * h2 + hh][m] = p / s;
    }

    {
        int eh = lane >> 3, qk = lane & 7;
        float ea[4] = {0, 0, 0, 0}, eb[4] = {0, 0, 0, 0};
        #pragma unroll 4
        for (int mm = 0; mm < 32; mm++) {
            float a = attnb[wid][eh][mm];
            u32 xA = *(const u32*)&enc[wid][mm][4 * qk];
            u32 xB = *(const u32*)&enc[wid][mm][4 * qk + 2];
            u32 yA = *(const u32*)&enc[wid][mm][4 * qk + 32];
            u32 yB = *(const u32*)&enc[wid][mm][4 * qk + 34];
            ea[0] += a * bfl(xA); ea[1] += a * bfh(xA);
            ea[2] += a * bfl(xB); ea[3] += a * bfh(xB);
            eb[0] += a * bfl(yA); eb[1] += a * bfh(yA);
            eb[2] += a * bfl(yB); eb[3] += a * bfh(yB);
        }
        #pragma unroll
        for (int i = 0; i < 4; i++) {
            ewb[wid][eh][4 * qk + i]      = ea[i];
            ewb[wid][eh][4 * qk + 32 + i] = eb[i];
        }
    }

    int myh = lane >> 3;
    float av0 = 0.f, av1 = 0.f;
    #pragma unroll
    for (int mm = 0; mm < 32; mm++) {
        float a = attnb[wid][myh][mm];
        av0 += a * bfl(vpre[mm]);
        av1 += a * bfh(vpre[mm]);
    }
    float ht0 = 0.f, ht1 = 0.f;
    #pragma unroll 8
    for (int k = 0; k < 64; k++) {
        float ew = ewb[wid][myh][k];
        float2 wv = *(const float2*)&Wtv[k * 128 + 2 * lane];
        ht0 += ew * wv.x;
        ht1 += ew * wv.y;
    }
    float2 bt2 = *(const float2*)&btv[2 * lane];
    float2 o;
    o.x = anyv ? (av0 + ht0 + bt2.x) : 0.0f;
    o.y = anyv ? (av1 + ht1 + bt2.y) : 0.0f;
    *(float2*)&hbuf[(size_t)n * 128 + 2 * lane] = o;
}

// ---------------------------------------------------------------------------
extern "C" void kernel_launch(void* const* d_in, const int* in_sizes, int n_in,
                              void* d_out, int out_size, void* d_ws, size_t ws_size,
                              hipStream_t stream)
{
    const float* x        = (const float*)d_in[0];
    const int*   neighbors= (const int*)  d_in[1];
    const float* times    = (const float*)d_in[2];
    const float* t        = (const float*)d_in[3];
    const float* Wk  = (const float*)d_in[4];
    const float* bk  = (const float*)d_in[5];
    const float* Wq  = (const float*)d_in[6];
    const float* bq  = (const float*)d_in[7];
    const float* Wv  = (const float*)d_in[8];
    const float* bv  = (const float*)d_in[9];
    const float* w0  = (const float*)d_in[10];
    const float* b0  = (const float*)d_in[11];
    const float* Wt  = (const float*)d_in[12];
    const float* Bt  = (const float*)d_in[13];
    const float* Wtk = (const float*)d_in[14];
    const float* btk = (const float*)d_in[15];
    const float* Wtq = (const float*)d_in[16];
    const float* btq = (const float*)d_in[17];
    const float* Wtv = (const float*)d_in[18];
    const float* btv = (const float*)d_in[19];
    const float* W1  = (const float*)d_in[20];
    const float* b1  = (const float*)d_in[21];
    const float* W2  = (const float*)d_in[22];
    const float* b2  = (const float*)d_in[23];

    float* ws = (float*)d_ws;
    const size_t NF = (size_t)NNODES * 128;
    float* Qtab  = ws;                                   // NF f32
    float* Ptab  = Qtab + NF;                            // NF f32
    float* hbuf  = Ptab + NF;                            // NF f32
    float* Utab  = hbuf + NF;                            // NF f32
    u16*   Kb    = (u16*)(Utab + NF);                    // NF bf16
    u16*   Vb    = Kb + NF;                              // NF bf16
    u16*   Gb    = Vb + NF;                              // N*512 bf16
    float* qbias = (float*)(Gb + (size_t)NNODES * 512);  // 128 f32
    u16*   Wts   = (u16*)(qbias + 128);                  // 6*16384 bf16

    wcast_kernel<<<6, 256, 0, stream>>>(Wk, Wq, Wv, W1, W2, Wts);
    prep_kernel<<<1, 128, 0, stream>>>(t, bq, btq, Wtq, w0, b0, Wt, Bt, qbias);

    gemm4m<<<dim3(NNODES / 128, 4), 256, 0, stream>>>(
        x, Wts, bk, qbias, bv, b1, Kb, Qtab, Vb, Ptab);

    gcalc_kernel<<<NNODES * 8 / 256, 256, 0, stream>>>(Qtab, Wtk, Gb);

    attn_kernel<<<NNODES / 4, 256, 0, stream>>>(neighbors, times, t,
                                                Kb, Qtab, Vb, Gb,
                                                btk, Wtv, btv, w0, b0, Wt, Bt,
                                                hbuf);

    gemm_m<<<NNODES / 128, 256, 0, stream>>>(hbuf, Wts + 4 * 16384, nullptr,
                                             Ptab, Utab, 1);
    gemm_m<<<NNODES / 128, 256, 0, stream>>>(Utab, Wts + 5 * 16384, b2,
                                             nullptr, (float*)d_out, 0);
}

// Round 5
// 150.926 us; speedup vs baseline: 1.0957x; 1.0957x over previous
//
#include <hip/hip_runtime.h>
#include <hip/hip_bf16.h>

#define NNODES 16384

typedef unsigned short u16;
typedef unsigned int   u32;
typedef __attribute__((ext_vector_type(8))) short bf16x8;
typedef __attribute__((ext_vector_type(4))) float f32x4;

__device__ __forceinline__ float bfl(u32 u) { return __uint_as_float(u << 16); }
__device__ __forceinline__ float bfh(u32 u) { return __uint_as_float(u & 0xffff0000u); }
__device__ __forceinline__ u16 f2b(float f) {
    u32 u = __float_as_uint(f);
    return (u16)((u + 0x7fffu + ((u >> 16) & 1u)) >> 16);
}
__device__ __forceinline__ u32 pk2(float a, float b) {
    return (u32)f2b(a) | ((u32)f2b(b) << 16);
}

#if defined(__has_builtin)
#if __has_builtin(__builtin_amdgcn_fdot2_f32_bf16)
#define HAVE_DOT2 1
#endif
#endif
#ifndef HAVE_DOT2
#define HAVE_DOT2 0
#endif

#if HAVE_DOT2
typedef __attribute__((ext_vector_type(2))) __bf16 bf16x2;
__device__ __forceinline__ float dot2b(u32 a, u32 b, float c) {
    return __builtin_amdgcn_fdot2_f32_bf16(__builtin_bit_cast(bf16x2, a),
                                           __builtin_bit_cast(bf16x2, b), c, false);
}
#else
__device__ __forceinline__ float dot2b(u32 a, u32 b, float c) {
    return c + bfl(a) * bfl(b) + bfh(a) * bfh(b);
}
#endif

// ---------------------------------------------------------------------------
// setup1: blocks 0..5 cast+transpose six 128x128 weights -> bf16 [col][k];
//         block 6: qbias[c] = bq + btq + enc(t) @ Wtq[:,c]
// ---------------------------------------------------------------------------
__global__ __launch_bounds__(256) void setup1_kernel(
    const float* __restrict__ Wk, const float* __restrict__ Wq,
    const float* __restrict__ Wv, const float* __restrict__ W1,
    const float* __restrict__ W2, u16* __restrict__ Wts,
    const float* __restrict__ t, const float* __restrict__ bq,
    const float* __restrict__ btq, const float* __restrict__ Wtq,
    const float* __restrict__ w0, const float* __restrict__ b0,
    const float* __restrict__ Wt, const float* __restrict__ Bt,
    float* __restrict__ qbias)
{
    int mat = blockIdx.x;
    int tt = threadIdx.x;
    if (mat < 6) {
        const float* src = (mat == 0) ? Wk : (mat == 1) ? Wq : (mat == 2) ? Wv
                         : (mat == 3) ? W1 : (mat == 4) ? (W1 + 128 * 128) : W2;
        u16* dst = Wts + (size_t)mat * 16384;
        #pragma unroll
        for (int i = 0; i < 64; i++) {
            int idx = i * 256 + tt;
            int k = idx >> 7, c = idx & 127;
            dst[c * 128 + k] = f2b(src[idx]);
        }
    } else {
        int c = tt;
        if (c < 128) {
            float tv = t[0];
            float s = bq[c] + btq[c];
            float e0 = w0[0] * tv + b0[0];
            s += e0 * Wtq[c];
            for (int k = 1; k < 64; k++) {
                float e = __sinf(tv * Wt[k - 1] + Bt[k - 1]);
                s += e * Wtq[k * 128 + c];
            }
            qbias[c] = s;
        }
    }
}

// ---------------------------------------------------------------------------
// setup2: blocks 0..63: WGt[hj][k] = sum_d Wq[k][h*16+d]*Wtk[j][h*16+d] (bf16)
//         block 64:     gb[hj] = sum_d qbias[h*16+d]*Wtk[j][h*16+d]  (f32)
//                       Wtvp[kp][c] = pack(Wtv[2kp][c], Wtv[2kp+1][c])
// ---------------------------------------------------------------------------
__global__ __launch_bounds__(256) void setup2_kernel(
    const float* __restrict__ Wq, const float* __restrict__ Wtk,
    const float* __restrict__ qbias, const float* __restrict__ Wtv,
    u16* __restrict__ WGt, float* __restrict__ gb, u32* __restrict__ Wtvp)
{
    int b = blockIdx.x, tt = threadIdx.x;
    if (b < 64) {
        int o0 = (b * 256 + tt) * 4;
        int hj = o0 >> 7, k0 = o0 & 127;
        int h = hj >> 6, j = hj & 63;
        const float* wtkr = Wtk + (size_t)j * 128 + h * 16;
        #pragma unroll
        for (int i = 0; i < 4; i++) {
            int k = k0 + i;
            const float* wqr = Wq + (size_t)k * 128 + h * 16;
            float s = 0.f;
            #pragma unroll
            for (int d = 0; d < 16; d++) s += wqr[d] * wtkr[d];
            WGt[(size_t)hj * 128 + k] = f2b(s);
        }
    } else {
        #pragma unroll
        for (int r = 0; r < 2; r++) {
            int hj = tt + r * 256;
            int h = hj >> 6, j = hj & 63;
            float s = 0.f;
            #pragma unroll
            for (int d = 0; d < 16; d++)
                s += qbias[h * 16 + d] * Wtk[(size_t)j * 128 + h * 16 + d];
            gb[hj] = s;
        }
        #pragma unroll
        for (int i = 0; i < 16; i++) {
            int idx = tt * 16 + i;
            int kp = idx >> 7, c = idx & 127;
            Wtvp[idx] = pk2(Wtv[(size_t)(2 * kp) * 128 + c],
                            Wtv[(size_t)(2 * kp + 1) * 128 + c]);
        }
    }
}

// ---------------------------------------------------------------------------
// Shared MFMA core: 128x128 tile, K=128, 4 waves, 16x16x32 bf16 MFMA.
// ---------------------------------------------------------------------------
__device__ __forceinline__ void mfma_core(
    const float* __restrict__ A, const u16* __restrict__ Wt,
    u16* As, u16* Ws, int rb, int t, f32x4 acc[2][8])
{
    u32* As32 = (u32*)As;
    u32* Ws32 = (u32*)Ws;
    const float2* Ap = (const float2*)(A + (size_t)rb * 128);
    const u32*   Wp = (const u32*)Wt;
    #pragma unroll
    for (int i = 0; i < 32; i++) {
        int idx2 = i * 256 + t;
        int r = idx2 >> 6, k2 = idx2 & 63;
        float2 v = Ap[idx2];
        As32[(r * 64 + k2) ^ ((r & 7) << 2)] = pk2(v.x, v.y);
    }
    #pragma unroll
    for (int i = 0; i < 32; i++) {
        int idx2 = i * 256 + t;
        int c = idx2 >> 6, k2 = idx2 & 63;
        Ws32[(c * 64 + k2) ^ ((c & 7) << 2)] = Wp[idx2];
    }
    __syncthreads();

    int wid = t >> 6, lane = t & 63;
    int l15 = lane & 15, lg = lane >> 4;
    int mb = wid * 32;
    int xo = (l15 & 7) << 3;

    #pragma unroll
    for (int mi = 0; mi < 2; mi++)
        #pragma unroll
        for (int nt = 0; nt < 8; nt++)
            acc[mi][nt] = (f32x4){0.f, 0.f, 0.f, 0.f};

    #pragma unroll
    for (int ks = 0; ks < 4; ks++) {
        int kq = ks * 32 + lg * 8;
        bf16x8 a0 = *(bf16x8*)&As[((mb + l15) * 128 + kq) ^ xo];
        bf16x8 a1 = *(bf16x8*)&As[((mb + 16 + l15) * 128 + kq) ^ xo];
        #pragma unroll
        for (int nt = 0; nt < 8; nt++) {
            bf16x8 b = *(bf16x8*)&Ws[((nt * 16 + l15) * 128 + kq) ^ xo];
            acc[0][nt] = __builtin_amdgcn_mfma_f32_16x16x32_bf16(a0, b, acc[0][nt], 0, 0, 0);
            acc[1][nt] = __builtin_amdgcn_mfma_f32_16x16x32_bf16(a1, b, acc[1][nt], 0, 0, 0);
        }
    }
}

// ---------------------------------------------------------------------------
// Fused 8-matrix MFMA GEMM over x. blockIdx.y:
//  0: Kb bf16   1: Qb bf16   2: Vb bf16   3: Ptab f32   4..7: Gb bf16 tiles
// ---------------------------------------------------------------------------
__global__ __launch_bounds__(256) void gemm8m(
    const float* __restrict__ x, const u16* __restrict__ Wts,
    const u16* __restrict__ WGt,
    const float* __restrict__ bk, const float* __restrict__ qbias,
    const float* __restrict__ bv, const float* __restrict__ b1,
    const float* __restrict__ gb,
    u16* __restrict__ Kb, u16* __restrict__ Qb,
    u16* __restrict__ Vb, float* __restrict__ Ptab, u16* __restrict__ Gb)
{
    __shared__ u16 As[128 * 128];
    __shared__ u16 Ws[128 * 128];
    int t = threadIdx.x;
    int rb = blockIdx.x * 128;
    int mat = blockIdx.y;
    const u16* Wt = (mat < 4) ? (Wts + (size_t)mat * 16384)
                              : (WGt + (size_t)(mat - 4) * 16384);
    const float* bias = (mat == 0) ? bk : (mat == 1) ? qbias : (mat == 2) ? bv
                      : (mat == 3) ? b1 : (gb + (mat - 4) * 128);

    f32x4 acc[2][8];
    mfma_core(x, Wt, As, Ws, rb, t, acc);

    int wid = t >> 6, lane = t & 63;
    int l15 = lane & 15, lg = lane >> 4;
    int mb = wid * 32;
    #pragma unroll
    for (int mi = 0; mi < 2; mi++) {
        #pragma unroll
        for (int nt = 0; nt < 8; nt++) {
            int c = nt * 16 + l15;
            float bvv = bias[c];
            #pragma unroll
            for (int j = 0; j < 4; j++) {
                size_t row = rb + mb + mi * 16 + lg * 4 + j;
                float v = acc[mi][nt][j] + bvv;
                if (mat == 3)      Ptab[row * 128 + c] = v;
                else if (mat < 3) {
                    u16* dst = (mat == 0) ? Kb : (mat == 1) ? Qb : Vb;
                    dst[row * 128 + c] = f2b(v);
                } else Gb[row * 512 + (size_t)(mat - 4) * 128 + c] = f2b(v);
            }
        }
    }
}

// ---------------------------------------------------------------------------
// Generic single MFMA GEMM: C = A@Wt (+bias) (+addsrc) (relu), f32 out.
// ---------------------------------------------------------------------------
__global__ __launch_bounds__(256) void gemm_m(
    const float* __restrict__ A, const u16* __restrict__ Wt,
    const float* __restrict__ bias, const float* __restrict__ addsrc,
    float* __restrict__ Cf, int relu)
{
    __shared__ u16 As[128 * 128];
    __shared__ u16 Ws[128 * 128];
    int t = threadIdx.x;
    int rb = blockIdx.x * 128;

    f32x4 acc[2][8];
    mfma_core(A, Wt, As, Ws, rb, t, acc);

    int wid = t >> 6, lane = t & 63;
    int l15 = lane & 15, lg = lane >> 4;
    int mb = wid * 32;
    #pragma unroll
    for (int mi = 0; mi < 2; mi++) {
        #pragma unroll
        for (int nt = 0; nt < 8; nt++) {
            int c = nt * 16 + l15;
            float bvv = bias ? bias[c] : 0.f;
            #pragma unroll
            for (int j = 0; j < 4; j++) {
                size_t row = rb + mb + mi * 16 + lg * 4 + j;
                float v = acc[mi][nt][j] + bvv;
                if (addsrc) v += addsrc[row * 128 + c];
                if (relu)   v = fmaxf(v, 0.f);
                Cf[row * 128 + c] = v;
            }
        }
    }
}

// ---------------------------------------------------------------------------
// Attention: one wave per node, 4 waves/block, wave-private LDS.
// Per-wave LDS 7808 B -> block 31232 B -> 5 blocks/CU.
// ---------------------------------------------------------------------------
__global__ __launch_bounds__(256, 5) void attn_kernel(
    const int*   __restrict__ neighbors, const float* __restrict__ times,
    const float* __restrict__ tptr,
    const u16* __restrict__ Kb, const u16* __restrict__ Qb,
    const u16* __restrict__ Vb, const u16* __restrict__ Gb,
    const float* __restrict__ btk,  const u32* __restrict__ Wtvp,
    const float* __restrict__ btv,
    const float* __restrict__ w0,   const float* __restrict__ b0,
    const float* __restrict__ Wt,   const float* __restrict__ Bt,
    float* __restrict__ hbuf)
{
    __shared__ u16   enc[4][32][66];    // 4224 B/wave
    __shared__ u32   gb16[4][256];      // 1024 B/wave (g pairs over k)
    __shared__ u32   qb[4][64];         //  256 B/wave (q pairs)
    __shared__ float attnb[4][8][33];   // 1056 B/wave
    __shared__ u32   ewp[4][8][34];     // 1088 B/wave (ewb pairs over k)
    __shared__ int   nbb[4][32];        //  128 B/wave
    __shared__ float cb_[4][8];         //   32 B/wave

    int t = threadIdx.x;
    int wid = t >> 6, lane = t & 63;
    int n = blockIdx.x * 4 + wid;
    float t0 = tptr[0];

    qb[wid][lane] = *((const u32*)Qb + (size_t)n * 64 + lane);
    *(int4*)&gb16[wid][4 * lane] = *(const int4*)((const u32*)Gb + (size_t)n * 256 + 4 * lane);

    int m = lane & 31, h2 = lane >> 5;
    if (lane < 32) nbb[wid][lane] = neighbors[n * 32 + lane];
    float tm = times[n * 32 + m];
    bool valid = (tm <= t0);

    // V preload (may be sunk by compiler; acceptable)
    u32 vpre[32];
    #pragma unroll
    for (int mm = 0; mm < 32; mm++) {
        int nbm = nbb[wid][mm];
        vpre[mm] = *(const u32*)(Vb + (size_t)nbm * 128 + 2 * lane);
    }

    // time encoding: lane (m,h2) computes k in [32*h2, 32*h2+32), packed pairs
    float W0 = w0[0], B0 = b0[0];
    int kbase = 32 * h2;
    #pragma unroll
    for (int i = 0; i < 16; i++) {
        int k0 = kbase + 2 * i;
        float v0 = (k0 == 0) ? (W0 * tm + B0) : __sinf(tm * Wt[k0 - 1] + Bt[k0 - 1]);
        float v1 = __sinf(tm * Wt[k0] + Bt[k0]);
        *(u32*)&enc[wid][m][k0] = pk2(v0, v1);
    }

    // cb_[h] = q_h . btk_h  (q from bf16 pairs)
    if (lane < 8) {
        float s = 0.f;
        #pragma unroll
        for (int j = 0; j < 8; j++) {
            u32 qp = qb[wid][lane * 8 + j];
            s += bfl(qp) * btk[lane * 16 + 2 * j] + bfh(qp) * btk[lane * 16 + 2 * j + 1];
        }
        cb_[wid][lane] = s;
    }

    // ---- scores: lane (m,h2) computes heads h = 4*h2+hh ----
    float acc[4] = {0, 0, 0, 0};
    int nb = nbb[wid][m];
    const int4* Kr4 = (const int4*)(Kb + (size_t)nb * 128 + h2 * 64);
    #pragma unroll
    for (int j = 0; j < 8; j++) {
        int4 kk = Kr4[j];
        int hh = j >> 1;
        int pairbase = (4 * h2 + hh) * 8 + (j & 1) * 4;
        int4 qq = *(const int4*)&qb[wid][pairbase];
        acc[hh] = dot2b((u32)kk.x, (u32)qq.x, acc[hh]);
        acc[hh] = dot2b((u32)kk.y, (u32)qq.y, acc[hh]);
        acc[hh] = dot2b((u32)kk.z, (u32)qq.z, acc[hh]);
        acc[hh] = dot2b((u32)kk.w, (u32)qq.w, acc[hh]);
    }
    #pragma unroll 4
    for (int c = 0; c < 16; c++) {
        u32 eA = *(const u32*)&enc[wid][m][4 * c];
        u32 eB = *(const u32*)&enc[wid][m][4 * c + 2];
        #pragma unroll
        for (int hh = 0; hh < 4; hh++) {
            int2 gg = *(const int2*)&gb16[wid][(4 * h2 + hh) * 32 + 2 * c];
            acc[hh] = dot2b(eA, (u32)gg.x, dot2b(eB, (u32)gg.y, acc[hh]));
        }
    }

    unsigned long long bal = __ballot(valid);
    bool anyv = (bal != 0ull);

    // ---- softmax over m within each 32-lane half ----
    #pragma unroll
    for (int hh = 0; hh < 4; hh++) {
        float sc = valid ? 0.25f * (acc[hh] + cb_[wid][4 * h2 + hh]) : -1e9f;
        float mx = sc;
        for (int off = 16; off > 0; off >>= 1)
            mx = fmaxf(mx, __shfl_xor(mx, off));
        float p = __expf(sc - mx);
        float s = p;
        for (int off = 16; off > 0; off >>= 1)
            s += __shfl_xor(s, off);
        attnb[wid][4 * h2 + hh][m] = p / s;
    }

    // ---- ewp[h][kp] = pack over k of sum_m attn[h][m] * enc[m][k] ----
    {
        int eh = lane >> 3, qk = lane & 7;
        float ea[4] = {0, 0, 0, 0}, eb[4] = {0, 0, 0, 0};
        #pragma unroll 4
        for (int mm = 0; mm < 32; mm++) {
            float a = attnb[wid][eh][mm];
            u32 xA = *(const u32*)&enc[wid][mm][4 * qk];
            u32 xB = *(const u32*)&enc[wid][mm][4 * qk + 2];
            u32 yA = *(const u32*)&enc[wid][mm][4 * qk + 32];
            u32 yB = *(const u32*)&enc[wid][mm][4 * qk + 34];
            ea[0] += a * bfl(xA); ea[1] += a * bfh(xA);
            ea[2] += a * bfl(xB); ea[3] += a * bfh(xB);
            eb[0] += a * bfl(yA); eb[1] += a * bfh(yA);
            eb[2] += a * bfl(yB); eb[3] += a * bfh(yB);
        }
        ewp[wid][eh][2 * qk]      = pk2(ea[0], ea[1]);
        ewp[wid][eh][2 * qk + 1]  = pk2(ea[2], ea[3]);
        ewp[wid][eh][2 * qk + 16] = pk2(eb[0], eb[1]);
        ewp[wid][eh][2 * qk + 17] = pk2(eb[2], eb[3]);
    }

    // ---- V aggregation; lane owns cols (2*lane, 2*lane+1), head = lane>>3 ----
    int myh = lane >> 3;
    float av0 = 0.f, av1 = 0.f;
    #pragma unroll
    for (int mm = 0; mm < 32; mm++) {
        float a = attnb[wid][myh][mm];
        av0 += a * bfl(vpre[mm]);
        av1 += a * bfh(vpre[mm]);
    }
    // ---- time-value term via packed pairs over k ----
    float ht0 = 0.f, ht1 = 0.f;
    #pragma unroll 8
    for (int kp = 0; kp < 32; kp++) {
        u32 ew = ewp[wid][myh][kp];
        int2 wv = *(const int2*)&Wtvp[kp * 128 + 2 * lane];
        ht0 = dot2b(ew, (u32)wv.x, ht0);
        ht1 = dot2b(ew, (u32)wv.y, ht1);
    }
    float2 bt2 = *(const float2*)&btv[2 * lane];
    float2 o;
    o.x = anyv ? (av0 + ht0 + bt2.x) : 0.0f;
    o.y = anyv ? (av1 + ht1 + bt2.y) : 0.0f;
    *(float2*)&hbuf[(size_t)n * 128 + 2 * lane] = o;
}

// ---------------------------------------------------------------------------
extern "C" void kernel_launch(void* const* d_in, const int* in_sizes, int n_in,
                              void* d_out, int out_size, void* d_ws, size_t ws_size,
                              hipStream_t stream)
{
    const float* x        = (const float*)d_in[0];
    const int*   neighbors= (const int*)  d_in[1];
    const float* times    = (const float*)d_in[2];
    const float* t        = (const float*)d_in[3];
    const float* Wk  = (const float*)d_in[4];
    const float* bk  = (const float*)d_in[5];
    const float* Wq  = (const float*)d_in[6];
    const float* bq  = (const float*)d_in[7];
    const float* Wv  = (const float*)d_in[8];
    const float* bv  = (const float*)d_in[9];
    const float* w0  = (const float*)d_in[10];
    const float* b0  = (const float*)d_in[11];
    const float* Wt  = (const float*)d_in[12];
    const float* Bt  = (const float*)d_in[13];
    const float* Wtk = (const float*)d_in[14];
    const float* btk = (const float*)d_in[15];
    const float* Wtq = (const float*)d_in[16];
    const float* btq = (const float*)d_in[17];
    const float* Wtv = (const float*)d_in[18];
    const float* btv = (const float*)d_in[19];
    const float* W1  = (const float*)d_in[20];
    const float* b1  = (const float*)d_in[21];
    const float* W2  = (const float*)d_in[22];
    const float* b2  = (const float*)d_in[23];

    float* ws = (float*)d_ws;
    const size_t NF = (size_t)NNODES * 128;
    float* Ptab  = ws;                                   // NF f32
    float* hbuf  = Ptab + NF;                            // NF f32
    float* Utab  = hbuf + NF;                            // NF f32
    u16*   Kb    = (u16*)(Utab + NF);                    // NF bf16
    u16*   Qb    = Kb + NF;                              // NF bf16
    u16*   Vb    = Qb + NF;                              // NF bf16
    u16*   Gb    = Vb + NF;                              // N*512 bf16
    float* qbias = (float*)(Gb + (size_t)NNODES * 512);  // 128 f32
    u16*   Wts   = (u16*)(qbias + 128);                  // 6*16384 bf16
    u16*   WGt   = Wts + 6 * 16384;                      // 65536 bf16
    float* gb    = (float*)(WGt + 65536);                // 512 f32
    u32*   Wtvp  = (u32*)(gb + 512);                     // 4096 u32

    setup1_kernel<<<7, 256, 0, stream>>>(Wk, Wq, Wv, W1, W2, Wts,
                                         t, bq, btq, Wtq, w0, b0, Wt, Bt, qbias);
    setup2_kernel<<<65, 256, 0, stream>>>(Wq, Wtk, qbias, Wtv, WGt, gb, Wtvp);

    gemm8m<<<dim3(NNODES / 128, 8), 256, 0, stream>>>(
        x, Wts, WGt, bk, qbias, bv, b1, gb, Kb, Qb, Vb, Ptab, Gb);

    attn_kernel<<<NNODES / 4, 256, 0, stream>>>(neighbors, times, t,
                                                Kb, Qb, Vb, Gb,
                                                btk, Wtvp, btv, w0, b0, Wt, Bt,
                                                hbuf);

    gemm_m<<<NNODES / 128, 256, 0, stream>>>(hbuf, Wts + 4 * 16384, nullptr,
                                             Ptab, Utab, 1);
    gemm_m<<<NNODES / 128, 256, 0, stream>>>(Utab, Wts + 5 * 16384, b2,
                                             nullptr, (float*)d_out, 0);
}

// Round 6
// 140.773 us; speedup vs baseline: 1.1747x; 1.0721x over previous
//
#include <hip/hip_runtime.h>
#include <hip/hip_bf16.h>

#define NNODES 16384

typedef unsigned short u16;
typedef unsigned int   u32;
typedef __attribute__((ext_vector_type(8))) short bf16x8;
typedef __attribute__((ext_vector_type(4))) float f32x4;

__device__ __forceinline__ float bfl(u32 u) { return __uint_as_float(u << 16); }
__device__ __forceinline__ float bfh(u32 u) { return __uint_as_float(u & 0xffff0000u); }
__device__ __forceinline__ u16 f2b(float f) {
    u32 u = __float_as_uint(f);
    return (u16)((u + 0x7fffu + ((u >> 16) & 1u)) >> 16);
}
__device__ __forceinline__ u32 pk2(float a, float b) {
    return (u32)f2b(a) | ((u32)f2b(b) << 16);
}

#if defined(__has_builtin)
#if __has_builtin(__builtin_amdgcn_fdot2_f32_bf16)
#define HAVE_DOT2 1
#endif
#endif
#ifndef HAVE_DOT2
#define HAVE_DOT2 0
#endif

#if HAVE_DOT2
typedef __attribute__((ext_vector_type(2))) __bf16 bf16x2;
__device__ __forceinline__ float dot2b(u32 a, u32 b, float c) {
    return __builtin_amdgcn_fdot2_f32_bf16(__builtin_bit_cast(bf16x2, a),
                                           __builtin_bit_cast(bf16x2, b), c, false);
}
#else
__device__ __forceinline__ float dot2b(u32 a, u32 b, float c) {
    return c + bfl(a) * bfl(b) + bfh(a) * bfh(b);
}
#endif

// ---------------------------------------------------------------------------
// setup_all: one wide kernel, 107 blocks.
//  b in [0,96):  weight cast+transpose (6 mats x 16 tiles) -> Wts bf16 [c][k]
//  b == 96:      qbias[c] = bq + btq + enc(t) @ Wtq[:,c]
//  b == 97:      gb[h*64+j] = sum_d qbias[h*16+d] * Wtk[j][h*16+d]
//  b == 98:      Wtvp[kp][c] = pack(Wtv[2kp][c], Wtv[2kp+1][c])
//  b in [99,107): WGt[(h*64+j)][k] = sum_d Wq[k][h*16+d]*Wtk[j][h*16+d] (bf16)
// ---------------------------------------------------------------------------
__global__ __launch_bounds__(256) void setup_all(
    const float* __restrict__ Wk, const float* __restrict__ Wq,
    const float* __restrict__ Wv, const float* __restrict__ W1,
    const float* __restrict__ W2,
    const float* __restrict__ t,  const float* __restrict__ bq,
    const float* __restrict__ btq,const float* __restrict__ Wtq,
    const float* __restrict__ w0, const float* __restrict__ b0,
    const float* __restrict__ Wt, const float* __restrict__ Bt,
    const float* __restrict__ Wtk,const float* __restrict__ Wtv,
    u16* __restrict__ Wts, float* __restrict__ qbias,
    float* __restrict__ gb, u32* __restrict__ Wtvp, u16* __restrict__ WGt)
{
    __shared__ float sb[128 * 17 + 64 * 17];
    int b = blockIdx.x, tt = threadIdx.x;

    if (b < 96) {
        // ---- weight transpose: mat b>>4, tile b&15 covers 8 output cols ----
        int mat = b >> 4, tile = b & 15;
        const float* src = (mat == 0) ? Wk : (mat == 1) ? Wq : (mat == 2) ? Wv
                         : (mat == 3) ? W1 : (mat == 4) ? (W1 + 128 * 128) : W2;
        u16* dst = Wts + (size_t)mat * 16384;
        #pragma unroll
        for (int i = 0; i < 4; i++) {
            int o = i * 256 + tt;
            int cl = o >> 7, k = o & 127;
            int c = tile * 8 + cl;
            dst[c * 128 + k] = f2b(src[k * 128 + c]);
        }
    } else if (b == 96 || b == 97) {
        // ---- qbias (b==96 stores it); b==97 derives gb from it ----
        float tv = t[0];
        if (tt < 64)
            sb[tt] = (tt == 0) ? (w0[0] * tv + b0[0])
                               : __sinf(tv * Wt[tt - 1] + Bt[tt - 1]);
        __syncthreads();
        if (tt < 128) {
            float s = bq[tt] + btq[tt];
            for (int k = 0; k < 64; k++)
                s += sb[k] * Wtq[k * 128 + tt];
            sb[64 + tt] = s;
            if (b == 96) qbias[tt] = s;
        }
        __syncthreads();
        if (b == 97) {
            #pragma unroll
            for (int r = 0; r < 2; r++) {
                int hj = tt + r * 256;
                int h = hj >> 6, j = hj & 63;
                float s = 0.f;
                #pragma unroll
                for (int d = 0; d < 16; d++)
                    s += sb[64 + h * 16 + d] * Wtk[(size_t)j * 128 + h * 16 + d];
                gb[hj] = s;
            }
        }
    } else if (b == 98) {
        // ---- Wtvp packing (coalesced) ----
        #pragma unroll
        for (int i = 0; i < 16; i++) {
            int idx = i * 256 + tt;
            int kp = idx >> 7, c = idx & 127;
            Wtvp[idx] = pk2(Wtv[(size_t)(2 * kp) * 128 + c],
                            Wtv[(size_t)(2 * kp + 1) * 128 + c]);
        }
    } else {
        // ---- WGt for head h = b-99 ----
        int h = b - 99;
        float* WqL  = sb;               // [128][17]
        float* WtkL = sb + 128 * 17;    // [64][17]
        #pragma unroll
        for (int i = 0; i < 8; i++) {
            int o = i * 256 + tt;
            int k = o >> 4, d = o & 15;
            WqL[k * 17 + d] = Wq[(size_t)k * 128 + h * 16 + d];
        }
        #pragma unroll
        for (int i = 0; i < 4; i++) {
            int o = i * 256 + tt;
            int j = o >> 4, d = o & 15;
            WtkL[j * 17 + d] = Wtk[(size_t)j * 128 + h * 16 + d];
        }
        __syncthreads();
        int j = tt >> 2, kb = (tt & 3) * 32;
        float wk[16];
        #pragma unroll
        for (int d = 0; d < 16; d++) wk[d] = WtkL[j * 17 + d];
        u32 out[16];
        #pragma unroll
        for (int kk2 = 0; kk2 < 16; kk2++) {
            int k = kb + 2 * kk2;
            float s0 = 0.f, s1 = 0.f;
            #pragma unroll
            for (int d = 0; d < 16; d++) {
                s0 += WqL[k * 17 + d] * wk[d];
                s1 += WqL[(k + 1) * 17 + d] * wk[d];
            }
            out[kk2] = pk2(s0, s1);
        }
        int4* dst = (int4*)(WGt + (size_t)(h * 64 + j) * 128 + kb);
        const int4* srcv = (const int4*)out;
        #pragma unroll
        for (int i = 0; i < 4; i++) dst[i] = srcv[i];
    }
}

// ---------------------------------------------------------------------------
// Shared MFMA core: 128x128 tile, K=128, 4 waves, 16x16x32 bf16 MFMA.
// ---------------------------------------------------------------------------
__device__ __forceinline__ void mfma_core(
    const float* __restrict__ A, const u16* __restrict__ Wt,
    u16* As, u16* Ws, int rb, int t, f32x4 acc[2][8])
{
    u32* As32 = (u32*)As;
    u32* Ws32 = (u32*)Ws;
    const float2* Ap = (const float2*)(A + (size_t)rb * 128);
    const u32*   Wp = (const u32*)Wt;
    #pragma unroll
    for (int i = 0; i < 32; i++) {
        int idx2 = i * 256 + t;
        int r = idx2 >> 6, k2 = idx2 & 63;
        float2 v = Ap[idx2];
        As32[(r * 64 + k2) ^ ((r & 7) << 2)] = pk2(v.x, v.y);
    }
    #pragma unroll
    for (int i = 0; i < 32; i++) {
        int idx2 = i * 256 + t;
        int c = idx2 >> 6, k2 = idx2 & 63;
        Ws32[(c * 64 + k2) ^ ((c & 7) << 2)] = Wp[idx2];
    }
    __syncthreads();

    int wid = t >> 6, lane = t & 63;
    int l15 = lane & 15, lg = lane >> 4;
    int mb = wid * 32;
    int xo = (l15 & 7) << 3;

    #pragma unroll
    for (int mi = 0; mi < 2; mi++)
        #pragma unroll
        for (int nt = 0; nt < 8; nt++)
            acc[mi][nt] = (f32x4){0.f, 0.f, 0.f, 0.f};

    #pragma unroll
    for (int ks = 0; ks < 4; ks++) {
        int kq = ks * 32 + lg * 8;
        bf16x8 a0 = *(bf16x8*)&As[((mb + l15) * 128 + kq) ^ xo];
        bf16x8 a1 = *(bf16x8*)&As[((mb + 16 + l15) * 128 + kq) ^ xo];
        #pragma unroll
        for (int nt = 0; nt < 8; nt++) {
            bf16x8 b = *(bf16x8*)&Ws[((nt * 16 + l15) * 128 + kq) ^ xo];
            acc[0][nt] = __builtin_amdgcn_mfma_f32_16x16x32_bf16(a0, b, acc[0][nt], 0, 0, 0);
            acc[1][nt] = __builtin_amdgcn_mfma_f32_16x16x32_bf16(a1, b, acc[1][nt], 0, 0, 0);
        }
    }
}

// ---------------------------------------------------------------------------
// Fused 8-matrix MFMA GEMM over x. blockIdx.y:
//  0: Kb bf16   1: Qb bf16   2: Vb bf16   3: Ptab f32   4..7: Gb bf16 tiles
// ---------------------------------------------------------------------------
__global__ __launch_bounds__(256) void gemm8m(
    const float* __restrict__ x, const u16* __restrict__ Wts,
    const u16* __restrict__ WGt,
    const float* __restrict__ bk, const float* __restrict__ qbias,
    const float* __restrict__ bv, const float* __restrict__ b1,
    const float* __restrict__ gb,
    u16* __restrict__ Kb, u16* __restrict__ Qb,
    u16* __restrict__ Vb, float* __restrict__ Ptab, u16* __restrict__ Gb)
{
    __shared__ u16 As[128 * 128];
    __shared__ u16 Ws[128 * 128];
    int t = threadIdx.x;
    int rb = blockIdx.x * 128;
    int mat = blockIdx.y;
    const u16* Wt = (mat < 4) ? (Wts + (size_t)mat * 16384)
                              : (WGt + (size_t)(mat - 4) * 16384);
    const float* bias = (mat == 0) ? bk : (mat == 1) ? qbias : (mat == 2) ? bv
                      : (mat == 3) ? b1 : (gb + (mat - 4) * 128);

    f32x4 acc[2][8];
    mfma_core(x, Wt, As, Ws, rb, t, acc);

    int wid = t >> 6, lane = t & 63;
    int l15 = lane & 15, lg = lane >> 4;
    int mb = wid * 32;
    #pragma unroll
    for (int mi = 0; mi < 2; mi++) {
        #pragma unroll
        for (int nt = 0; nt < 8; nt++) {
            int c = nt * 16 + l15;
            float bvv = bias[c];
            #pragma unroll
            for (int j = 0; j < 4; j++) {
                size_t row = rb + mb + mi * 16 + lg * 4 + j;
                float v = acc[mi][nt][j] + bvv;
                if (mat == 3)      Ptab[row * 128 + c] = v;
                else if (mat < 3) {
                    u16* dst = (mat == 0) ? Kb : (mat == 1) ? Qb : Vb;
                    dst[row * 128 + c] = f2b(v);
                } else Gb[row * 512 + (size_t)(mat - 4) * 128 + c] = f2b(v);
            }
        }
    }
}

// ---------------------------------------------------------------------------
// Generic single MFMA GEMM: C = A@Wt (+bias) (+addsrc) (relu), f32 out.
// ---------------------------------------------------------------------------
__global__ __launch_bounds__(256) void gemm_m(
    const float* __restrict__ A, const u16* __restrict__ Wt,
    const float* __restrict__ bias, const float* __restrict__ addsrc,
    float* __restrict__ Cf, int relu)
{
    __shared__ u16 As[128 * 128];
    __shared__ u16 Ws[128 * 128];
    int t = threadIdx.x;
    int rb = blockIdx.x * 128;

    f32x4 acc[2][8];
    mfma_core(A, Wt, As, Ws, rb, t, acc);

    int wid = t >> 6, lane = t & 63;
    int l15 = lane & 15, lg = lane >> 4;
    int mb = wid * 32;
    #pragma unroll
    for (int mi = 0; mi < 2; mi++) {
        #pragma unroll
        for (int nt = 0; nt < 8; nt++) {
            int c = nt * 16 + l15;
            float bvv = bias ? bias[c] : 0.f;
            #pragma unroll
            for (int j = 0; j < 4; j++) {
                size_t row = rb + mb + mi * 16 + lg * 4 + j;
                float v = acc[mi][nt][j] + bvv;
                if (addsrc) v += addsrc[row * 128 + c];
                if (relu)   v = fmaxf(v, 0.f);
                Cf[row * 128 + c] = v;
            }
        }
    }
}

// ---------------------------------------------------------------------------
// Attention: one wave per node, 4 waves/block, wave-private LDS.
// (unchanged from Round 5)
// ---------------------------------------------------------------------------
__global__ __launch_bounds__(256, 5) void attn_kernel(
    const int*   __restrict__ neighbors, const float* __restrict__ times,
    const float* __restrict__ tptr,
    const u16* __restrict__ Kb, const u16* __restrict__ Qb,
    const u16* __restrict__ Vb, const u16* __restrict__ Gb,
    const float* __restrict__ btk,  const u32* __restrict__ Wtvp,
    const float* __restrict__ btv,
    const float* __restrict__ w0,   const float* __restrict__ b0,
    const float* __restrict__ Wt,   const float* __restrict__ Bt,
    float* __restrict__ hbuf)
{
    __shared__ u16   enc[4][32][66];
    __shared__ u32   gb16[4][256];
    __shared__ u32   qb[4][64];
    __shared__ float attnb[4][8][33];
    __shared__ u32   ewp[4][8][34];
    __shared__ int   nbb[4][32];
    __shared__ float cb_[4][8];

    int t = threadIdx.x;
    int wid = t >> 6, lane = t & 63;
    int n = blockIdx.x * 4 + wid;
    float t0 = tptr[0];

    qb[wid][lane] = *((const u32*)Qb + (size_t)n * 64 + lane);
    *(int4*)&gb16[wid][4 * lane] = *(const int4*)((const u32*)Gb + (size_t)n * 256 + 4 * lane);

    int m = lane & 31, h2 = lane >> 5;
    if (lane < 32) nbb[wid][lane] = neighbors[n * 32 + lane];
    float tm = times[n * 32 + m];
    bool valid = (tm <= t0);

    u32 vpre[32];
    #pragma unroll
    for (int mm = 0; mm < 32; mm++) {
        int nbm = nbb[wid][mm];
        vpre[mm] = *(const u32*)(Vb + (size_t)nbm * 128 + 2 * lane);
    }

    float W0 = w0[0], B0 = b0[0];
    int kbase = 32 * h2;
    #pragma unroll
    for (int i = 0; i < 16; i++) {
        int k0 = kbase + 2 * i;
        float v0 = (k0 == 0) ? (W0 * tm + B0) : __sinf(tm * Wt[k0 - 1] + Bt[k0 - 1]);
        float v1 = __sinf(tm * Wt[k0] + Bt[k0]);
        *(u32*)&enc[wid][m][k0] = pk2(v0, v1);
    }

    if (lane < 8) {
        float s = 0.f;
        #pragma unroll
        for (int j = 0; j < 8; j++) {
            u32 qp = qb[wid][lane * 8 + j];
            s += bfl(qp) * btk[lane * 16 + 2 * j] + bfh(qp) * btk[lane * 16 + 2 * j + 1];
        }
        cb_[wid][lane] = s;
    }

    float acc[4] = {0, 0, 0, 0};
    int nb = nbb[wid][m];
    const int4* Kr4 = (const int4*)(Kb + (size_t)nb * 128 + h2 * 64);
    #pragma unroll
    for (int j = 0; j < 8; j++) {
        int4 kk = Kr4[j];
        int hh = j >> 1;
        int pairbase = (4 * h2 + hh) * 8 + (j & 1) * 4;
        int4 qq = *(const int4*)&qb[wid][pairbase];
        acc[hh] = dot2b((u32)kk.x, (u32)qq.x, acc[hh]);
        acc[hh] = dot2b((u32)kk.y, (u32)qq.y, acc[hh]);
        acc[hh] = dot2b((u32)kk.z, (u32)qq.z, acc[hh]);
        acc[hh] = dot2b((u32)kk.w, (u32)qq.w, acc[hh]);
    }
    #pragma unroll 4
    for (int c = 0; c < 16; c++) {
        u32 eA = *(const u32*)&enc[wid][m][4 * c];
        u32 eB = *(const u32*)&enc[wid][m][4 * c + 2];
        #pragma unroll
        for (int hh = 0; hh < 4; hh++) {
            int2 gg = *(const int2*)&gb16[wid][(4 * h2 + hh) * 32 + 2 * c];
            acc[hh] = dot2b(eA, (u32)gg.x, dot2b(eB, (u32)gg.y, acc[hh]));
        }
    }

    unsigned long long bal = __ballot(valid);
    bool anyv = (bal != 0ull);

    #pragma unroll
    for (int hh = 0; hh < 4; hh++) {
        float sc = valid ? 0.25f * (acc[hh] + cb_[wid][4 * h2 + hh]) : -1e9f;
        float mx = sc;
        for (int off = 16; off > 0; off >>= 1)
            mx = fmaxf(mx, __shfl_xor(mx, off));
        float p = __expf(sc - mx);
        float s = p;
        for (int off = 16; off > 0; off >>= 1)
            s += __shfl_xor(s, off);
        attnb[wid][4 * h2 + hh][m] = p / s;
    }

    {
        int eh = lane >> 3, qk = lane & 7;
        float ea[4] = {0, 0, 0, 0}, eb[4] = {0, 0, 0, 0};
        #pragma unroll 4
        for (int mm = 0; mm < 32; mm++) {
            float a = attnb[wid][eh][mm];
            u32 xA = *(const u32*)&enc[wid][mm][4 * qk];
            u32 xB = *(const u32*)&enc[wid][mm][4 * qk + 2];
            u32 yA = *(const u32*)&enc[wid][mm][4 * qk + 32];
            u32 yB = *(const u32*)&enc[wid][mm][4 * qk + 34];
            ea[0] += a * bfl(xA); ea[1] += a * bfh(xA);
            ea[2] += a * bfl(xB); ea[3] += a * bfh(xB);
            eb[0] += a * bfl(yA); eb[1] += a * bfh(yA);
            eb[2] += a * bfl(yB); eb[3] += a * bfh(yB);
        }
        ewp[wid][eh][2 * qk]      = pk2(ea[0], ea[1]);
        ewp[wid][eh][2 * qk + 1]  = pk2(ea[2], ea[3]);
        ewp[wid][eh][2 * qk + 16] = pk2(eb[0], eb[1]);
        ewp[wid][eh][2 * qk + 17] = pk2(eb[2], eb[3]);
    }

    int myh = lane >> 3;
    float av0 = 0.f, av1 = 0.f;
    #pragma unroll
    for (int mm = 0; mm < 32; mm++) {
        float a = attnb[wid][myh][mm];
        av0 += a * bfl(vpre[mm]);
        av1 += a * bfh(vpre[mm]);
    }
    float ht0 = 0.f, ht1 = 0.f;
    #pragma unroll 8
    for (int kp = 0; kp < 32; kp++) {
        u32 ew = ewp[wid][myh][kp];
        int2 wv = *(const int2*)&Wtvp[kp * 128 + 2 * lane];
        ht0 = dot2b(ew, (u32)wv.x, ht0);
        ht1 = dot2b(ew, (u32)wv.y, ht1);
    }
    float2 bt2 = *(const float2*)&btv[2 * lane];
    float2 o;
    o.x = anyv ? (av0 + ht0 + bt2.x) : 0.0f;
    o.y = anyv ? (av1 + ht1 + bt2.y) : 0.0f;
    *(float2*)&hbuf[(size_t)n * 128 + 2 * lane] = o;
}

// ---------------------------------------------------------------------------
extern "C" void kernel_launch(void* const* d_in, const int* in_sizes, int n_in,
                              void* d_out, int out_size, void* d_ws, size_t ws_size,
                              hipStream_t stream)
{
    const float* x        = (const float*)d_in[0];
    const int*   neighbors= (const int*)  d_in[1];
    const float* times    = (const float*)d_in[2];
    const float* t        = (const float*)d_in[3];
    const float* Wk  = (const float*)d_in[4];
    const float* bk  = (const float*)d_in[5];
    const float* Wq  = (const float*)d_in[6];
    const float* bq  = (const float*)d_in[7];
    const float* Wv  = (const float*)d_in[8];
    const float* bv  = (const float*)d_in[9];
    const float* w0  = (const float*)d_in[10];
    const float* b0  = (const float*)d_in[11];
    const float* Wt  = (const float*)d_in[12];
    const float* Bt  = (const float*)d_in[13];
    const float* Wtk = (const float*)d_in[14];
    const float* btk = (const float*)d_in[15];
    const float* Wtq = (const float*)d_in[16];
    const float* btq = (const float*)d_in[17];
    const float* Wtv = (const float*)d_in[18];
    const float* btv = (const float*)d_in[19];
    const float* W1  = (const float*)d_in[20];
    const float* b1  = (const float*)d_in[21];
    const float* W2  = (const float*)d_in[22];
    const float* b2  = (const float*)d_in[23];

    float* ws = (float*)d_ws;
    const size_t NF = (size_t)NNODES * 128;
    float* Ptab  = ws;                                   // NF f32
    float* hbuf  = Ptab + NF;                            // NF f32
    float* Utab  = hbuf + NF;                            // NF f32
    u16*   Kb    = (u16*)(Utab + NF);                    // NF bf16
    u16*   Qb    = Kb + NF;                              // NF bf16
    u16*   Vb    = Qb + NF;                              // NF bf16
    u16*   Gb    = Vb + NF;                              // N*512 bf16
    float* qbias = (float*)(Gb + (size_t)NNODES * 512);  // 128 f32
    u16*   Wts   = (u16*)(qbias + 128);                  // 6*16384 bf16
    u16*   WGt   = Wts + 6 * 16384;                      // 65536 bf16
    float* gb    = (float*)(WGt + 65536);                // 512 f32
    u32*   Wtvp  = (u32*)(gb + 512);                     // 4096 u32

    setup_all<<<107, 256, 0, stream>>>(Wk, Wq, Wv, W1, W2,
                                       t, bq, btq, Wtq, w0, b0, Wt, Bt,
                                       Wtk, Wtv,
                                       Wts, qbias, gb, Wtvp, WGt);

    gemm8m<<<dim3(NNODES / 128, 8), 256, 0, stream>>>(
        x, Wts, WGt, bk, qbias, bv, b1, gb, Kb, Qb, Vb, Ptab, Gb);

    attn_kernel<<<NNODES / 4, 256, 0, stream>>>(neighbors, times, t,
                                                Kb, Qb, Vb, Gb,
                                                btk, Wtvp, btv, w0, b0, Wt, Bt,
                                                hbuf);

    gemm_m<<<NNODES / 128, 256, 0, stream>>>(hbuf, Wts + 4 * 16384, nullptr,
                                             Ptab, Utab, 1);
    gemm_m<<<NNODES / 128, 256, 0, stream>>>(Utab, Wts + 5 * 16384, b2,
                                             nullptr, (float*)d_out, 0);
}

// Round 7
// 121.779 us; speedup vs baseline: 1.3579x; 1.1560x over previous
//
#include <hip/hip_runtime.h>
#include <hip/hip_bf16.h>

#define NNODES 16384

typedef unsigned short u16;
typedef unsigned int   u32;
typedef __attribute__((ext_vector_type(8))) short bf16x8;
typedef __attribute__((ext_vector_type(4))) float f32x4;

__device__ __forceinline__ float bfl(u32 u) { return __uint_as_float(u << 16); }
__device__ __forceinline__ float bfh(u32 u) { return __uint_as_float(u & 0xffff0000u); }
__device__ __forceinline__ u16 f2b(float f) {
    u32 u = __float_as_uint(f);
    return (u16)((u + 0x7fffu + ((u >> 16) & 1u)) >> 16);
}
__device__ __forceinline__ u32 pk2(float a, float b) {
    return (u32)f2b(a) | ((u32)f2b(b) << 16);
}
__device__ __forceinline__ bf16x8 bcast8(int4 v) {
    return __builtin_bit_cast(bf16x8, v);
}

#if defined(__has_builtin)
#if __has_builtin(__builtin_amdgcn_fdot2_f32_bf16)
#define HAVE_DOT2 1
#endif
#endif
#ifndef HAVE_DOT2
#define HAVE_DOT2 0
#endif

#if HAVE_DOT2
typedef __attribute__((ext_vector_type(2))) __bf16 bf16x2;
__device__ __forceinline__ float dot2b(u32 a, u32 b, float c) {
    return __builtin_amdgcn_fdot2_f32_bf16(__builtin_bit_cast(bf16x2, a),
                                           __builtin_bit_cast(bf16x2, b), c, false);
}
#else
__device__ __forceinline__ float dot2b(u32 a, u32 b, float c) {
    return c + bfl(a) * bfl(b) + bfh(a) * bfh(b);
}
#endif

// ---------------------------------------------------------------------------
// setup_all: one wide kernel, 107 blocks. (unchanged from Round 6)
// ---------------------------------------------------------------------------
__global__ __launch_bounds__(256) void setup_all(
    const float* __restrict__ Wk, const float* __restrict__ Wq,
    const float* __restrict__ Wv, const float* __restrict__ W1,
    const float* __restrict__ W2,
    const float* __restrict__ t,  const float* __restrict__ bq,
    const float* __restrict__ btq,const float* __restrict__ Wtq,
    const float* __restrict__ w0, const float* __restrict__ b0,
    const float* __restrict__ Wt, const float* __restrict__ Bt,
    const float* __restrict__ Wtk,const float* __restrict__ Wtv,
    u16* __restrict__ Wts, float* __restrict__ qbias,
    float* __restrict__ gb, u32* __restrict__ Wtvp, u16* __restrict__ WGt)
{
    __shared__ float sb[128 * 17 + 64 * 17];
    int b = blockIdx.x, tt = threadIdx.x;

    if (b < 96) {
        int mat = b >> 4, tile = b & 15;
        const float* src = (mat == 0) ? Wk : (mat == 1) ? Wq : (mat == 2) ? Wv
                         : (mat == 3) ? W1 : (mat == 4) ? (W1 + 128 * 128) : W2;
        u16* dst = Wts + (size_t)mat * 16384;
        #pragma unroll
        for (int i = 0; i < 4; i++) {
            int o = i * 256 + tt;
            int cl = o >> 7, k = o & 127;
            int c = tile * 8 + cl;
            dst[c * 128 + k] = f2b(src[k * 128 + c]);
        }
    } else if (b == 96 || b == 97) {
        float tv = t[0];
        if (tt < 64)
            sb[tt] = (tt == 0) ? (w0[0] * tv + b0[0])
                               : __sinf(tv * Wt[tt - 1] + Bt[tt - 1]);
        __syncthreads();
        if (tt < 128) {
            float s = bq[tt] + btq[tt];
            for (int k = 0; k < 64; k++)
                s += sb[k] * Wtq[k * 128 + tt];
            sb[64 + tt] = s;
            if (b == 96) qbias[tt] = s;
        }
        __syncthreads();
        if (b == 97) {
            #pragma unroll
            for (int r = 0; r < 2; r++) {
                int hj = tt + r * 256;
                int h = hj >> 6, j = hj & 63;
                float s = 0.f;
                #pragma unroll
                for (int d = 0; d < 16; d++)
                    s += sb[64 + h * 16 + d] * Wtk[(size_t)j * 128 + h * 16 + d];
                gb[hj] = s;
            }
        }
    } else if (b == 98) {
        #pragma unroll
        for (int i = 0; i < 16; i++) {
            int idx = i * 256 + tt;
            int kp = idx >> 7, c = idx & 127;
            Wtvp[idx] = pk2(Wtv[(size_t)(2 * kp) * 128 + c],
                            Wtv[(size_t)(2 * kp + 1) * 128 + c]);
        }
    } else {
        int h = b - 99;
        float* WqL  = sb;
        float* WtkL = sb + 128 * 17;
        #pragma unroll
        for (int i = 0; i < 8; i++) {
            int o = i * 256 + tt;
            int k = o >> 4, d = o & 15;
            WqL[k * 17 + d] = Wq[(size_t)k * 128 + h * 16 + d];
        }
        #pragma unroll
        for (int i = 0; i < 4; i++) {
            int o = i * 256 + tt;
            int j = o >> 4, d = o & 15;
            WtkL[j * 17 + d] = Wtk[(size_t)j * 128 + h * 16 + d];
        }
        __syncthreads();
        int j = tt >> 2, kb = (tt & 3) * 32;
        float wk[16];
        #pragma unroll
        for (int d = 0; d < 16; d++) wk[d] = WtkL[j * 17 + d];
        u32 out[16];
        #pragma unroll
        for (int kk2 = 0; kk2 < 16; kk2++) {
            int k = kb + 2 * kk2;
            float s0 = 0.f, s1 = 0.f;
            #pragma unroll
            for (int d = 0; d < 16; d++) {
                s0 += WqL[k * 17 + d] * wk[d];
                s1 += WqL[(k + 1) * 17 + d] * wk[d];
            }
            out[kk2] = pk2(s0, s1);
        }
        int4* dst = (int4*)(WGt + (size_t)(h * 64 + j) * 128 + kb);
        const int4* srcv = (const int4*)out;
        #pragma unroll
        for (int i = 0; i < 4; i++) dst[i] = srcv[i];
    }
}

// ---------------------------------------------------------------------------
// Shared MFMA core: 128x128 tile, K=128, 4 waves, 16x16x32 bf16 MFMA.
// ---------------------------------------------------------------------------
__device__ __forceinline__ void mfma_core(
    const float* __restrict__ A, const u16* __restrict__ Wt,
    u16* As, u16* Ws, int rb, int t, f32x4 acc[2][8])
{
    u32* As32 = (u32*)As;
    u32* Ws32 = (u32*)Ws;
    const float2* Ap = (const float2*)(A + (size_t)rb * 128);
    const u32*   Wp = (const u32*)Wt;
    #pragma unroll
    for (int i = 0; i < 32; i++) {
        int idx2 = i * 256 + t;
        int r = idx2 >> 6, k2 = idx2 & 63;
        float2 v = Ap[idx2];
        As32[(r * 64 + k2) ^ ((r & 7) << 2)] = pk2(v.x, v.y);
    }
    #pragma unroll
    for (int i = 0; i < 32; i++) {
        int idx2 = i * 256 + t;
        int c = idx2 >> 6, k2 = idx2 & 63;
        Ws32[(c * 64 + k2) ^ ((c & 7) << 2)] = Wp[idx2];
    }
    __syncthreads();

    int wid = t >> 6, lane = t & 63;
    int l15 = lane & 15, lg = lane >> 4;
    int mb = wid * 32;
    int xo = (l15 & 7) << 3;

    #pragma unroll
    for (int mi = 0; mi < 2; mi++)
        #pragma unroll
        for (int nt = 0; nt < 8; nt++)
            acc[mi][nt] = (f32x4){0.f, 0.f, 0.f, 0.f};

    #pragma unroll
    for (int ks = 0; ks < 4; ks++) {
        int kq = ks * 32 + lg * 8;
        bf16x8 a0 = *(bf16x8*)&As[((mb + l15) * 128 + kq) ^ xo];
        bf16x8 a1 = *(bf16x8*)&As[((mb + 16 + l15) * 128 + kq) ^ xo];
        #pragma unroll
        for (int nt = 0; nt < 8; nt++) {
            bf16x8 b = *(bf16x8*)&Ws[((nt * 16 + l15) * 128 + kq) ^ xo];
            acc[0][nt] = __builtin_amdgcn_mfma_f32_16x16x32_bf16(a0, b, acc[0][nt], 0, 0, 0);
            acc[1][nt] = __builtin_amdgcn_mfma_f32_16x16x32_bf16(a1, b, acc[1][nt], 0, 0, 0);
        }
    }
}

// ---------------------------------------------------------------------------
// Fused 8-matrix MFMA GEMM over x. (unchanged from Round 6)
// ---------------------------------------------------------------------------
__global__ __launch_bounds__(256) void gemm8m(
    const float* __restrict__ x, const u16* __restrict__ Wts,
    const u16* __restrict__ WGt,
    const float* __restrict__ bk, const float* __restrict__ qbias,
    const float* __restrict__ bv, const float* __restrict__ b1,
    const float* __restrict__ gb,
    u16* __restrict__ Kb, u16* __restrict__ Qb,
    u16* __restrict__ Vb, float* __restrict__ Ptab, u16* __restrict__ Gb)
{
    __shared__ u16 As[128 * 128];
    __shared__ u16 Ws[128 * 128];
    int t = threadIdx.x;
    int rb = blockIdx.x * 128;
    int mat = blockIdx.y;
    const u16* Wt = (mat < 4) ? (Wts + (size_t)mat * 16384)
                              : (WGt + (size_t)(mat - 4) * 16384);
    const float* bias = (mat == 0) ? bk : (mat == 1) ? qbias : (mat == 2) ? bv
                      : (mat == 3) ? b1 : (gb + (mat - 4) * 128);

    f32x4 acc[2][8];
    mfma_core(x, Wt, As, Ws, rb, t, acc);

    int wid = t >> 6, lane = t & 63;
    int l15 = lane & 15, lg = lane >> 4;
    int mb = wid * 32;
    #pragma unroll
    for (int mi = 0; mi < 2; mi++) {
        #pragma unroll
        for (int nt = 0; nt < 8; nt++) {
            int c = nt * 16 + l15;
            float bvv = bias[c];
            #pragma unroll
            for (int j = 0; j < 4; j++) {
                size_t row = rb + mb + mi * 16 + lg * 4 + j;
                float v = acc[mi][nt][j] + bvv;
                if (mat == 3)      Ptab[row * 128 + c] = v;
                else if (mat < 3) {
                    u16* dst = (mat == 0) ? Kb : (mat == 1) ? Qb : Vb;
                    dst[row * 128 + c] = f2b(v);
                } else Gb[row * 512 + (size_t)(mat - 4) * 128 + c] = f2b(v);
            }
        }
    }
}

// ---------------------------------------------------------------------------
// Generic single MFMA GEMM: C = A@Wt (+bias) (+addsrc) (relu), f32 out.
// ---------------------------------------------------------------------------
__global__ __launch_bounds__(256) void gemm_m(
    const float* __restrict__ A, const u16* __restrict__ Wt,
    const float* __restrict__ bias, const float* __restrict__ addsrc,
    float* __restrict__ Cf, int relu)
{
    __shared__ u16 As[128 * 128];
    __shared__ u16 Ws[128 * 128];
    int t = threadIdx.x;
    int rb = blockIdx.x * 128;

    f32x4 acc[2][8];
    mfma_core(A, Wt, As, Ws, rb, t, acc);

    int wid = t >> 6, lane = t & 63;
    int l15 = lane & 15, lg = lane >> 4;
    int mb = wid * 32;
    #pragma unroll
    for (int mi = 0; mi < 2; mi++) {
        #pragma unroll
        for (int nt = 0; nt < 8; nt++) {
            int c = nt * 16 + l15;
            float bvv = bias ? bias[c] : 0.f;
            #pragma unroll
            for (int j = 0; j < 4; j++) {
                size_t row = rb + mb + mi * 16 + lg * 4 + j;
                float v = acc[mi][nt][j] + bvv;
                if (addsrc) v += addsrc[row * 128 + c];
                if (relu)   v = fmaxf(v, 0.f);
                Cf[row * 128 + c] = v;
            }
        }
    }
}

// ---------------------------------------------------------------------------
// Attention: one wave per node, 4 waves/block, wave-private LDS, no barriers.
// Scores (QK + enc.g) and ewp (P^T @ enc) on MFMA; value path on VALU.
// LDS 32640 B/block.
// Fragment layouts (mirror mfma_core): A: row=l15, k=8*lg+j; B: col=l15,
// k=8*lg+j; C: col=l15, row=4*lg+j.
// ---------------------------------------------------------------------------
__global__ __launch_bounds__(256, 4) void attn_kernel(
    const int*   __restrict__ neighbors, const float* __restrict__ times,
    const float* __restrict__ tptr,
    const u16* __restrict__ Kb, const u16* __restrict__ Qb,
    const u16* __restrict__ Vb, const u16* __restrict__ Gb,
    const float* __restrict__ btk,  const u32* __restrict__ Wtvp,
    const float* __restrict__ btv,
    const float* __restrict__ w0,   const float* __restrict__ b0,
    const float* __restrict__ Wt,   const float* __restrict__ Bt,
    float* __restrict__ hbuf)
{
    __shared__ u16   enc[4][32][72];    // 4608 B/wave (stride 144B: b128-aligned rows)
    __shared__ u32   gbp[4][8][32];     // 1024 B/wave (g bf16 pairs, [h][kpair])
    __shared__ u32   qb[4][64];         //  256 B/wave
    __shared__ float pbuf[4][8][33];    // 1056 B/wave (P f32, [h][m])
    __shared__ u16   ewp[4][8][66];     // 1056 B/wave (ewb bf16, [h][k])
    __shared__ int   nbb[4][32];        //  128 B/wave
    __shared__ float cb_[4][8];         //   32 B/wave   (total 8160*4 = 32640)

    int t = threadIdx.x;
    int wid = t >> 6, lane = t & 63;
    int n = blockIdx.x * 4 + wid;
    float t0 = tptr[0];
    int l15 = lane & 15, lg = lane >> 4;

    qb[wid][lane] = ((const u32*)Qb)[(size_t)n * 64 + lane];
    {
        int4 g4 = *(const int4*)((const u32*)Gb + (size_t)n * 256 + 4 * lane);
        const u32* gw = (const u32*)&g4;
        #pragma unroll
        for (int i = 0; i < 4; i++) {
            int q4 = 4 * lane + i;
            gbp[wid][q4 >> 5][q4 & 31] = gw[i];
        }
    }

    int m = lane & 31, h2 = lane >> 5;
    if (lane < 32) nbb[wid][lane] = neighbors[n * 32 + lane];
    float tm = times[n * 32 + m];
    bool valid = (tm <= t0);
    unsigned long long bal = __ballot(valid);
    bool anyv = (bal != 0ull);

    // ---- V preload ----
    u32 vpre[32];
    #pragma unroll
    for (int mm = 0; mm < 32; mm++) {
        int nbm = nbb[wid][mm];
        vpre[mm] = *(const u32*)(Vb + (size_t)nbm * 128 + 2 * lane);
    }

    // ---- time encoding (unchanged math; rows padded to 72 u16) ----
    float W0 = w0[0], B0 = b0[0];
    int kbase = 32 * h2;
    #pragma unroll
    for (int i = 0; i < 16; i++) {
        int k0 = kbase + 2 * i;
        float v0 = (k0 == 0) ? (W0 * tm + B0) : __sinf(tm * Wt[k0 - 1] + Bt[k0 - 1]);
        float v1 = __sinf(tm * Wt[k0] + Bt[k0]);
        *(u32*)&enc[wid][m][k0] = pk2(v0, v1);
    }

    // cb_[h] = q_h . btk_h
    if (lane < 8) {
        float s = 0.f;
        #pragma unroll
        for (int j = 0; j < 8; j++) {
            u32 qp = qb[wid][lane * 8 + j];
            s += bfl(qp) * btk[lane * 16 + 2 * j] + bfh(qp) * btk[lane * 16 + 2 * j + 1];
        }
        cb_[wid][lane] = s;
    }

    // ================= scores via MFMA =================
    f32x4 accS[2];
    accS[0] = (f32x4){0.f, 0.f, 0.f, 0.f};
    accS[1] = (f32x4){0.f, 0.f, 0.f, 0.f};

    // QK: scores[m,h] += K[m,:] @ Qexp[:,h]  (Qexp block-diagonal)
    int nb0 = nbb[wid][l15];
    int nb1 = nbb[wid][l15 + 16];
    const u16* K0 = Kb + (size_t)nb0 * 128;
    const u16* K1 = Kb + (size_t)nb1 * 128;
    const int4 zero4 = {0, 0, 0, 0};
    #pragma unroll
    for (int ks = 0; ks < 4; ks++) {
        bf16x8 qf = bcast8((l15 == ks * 2 + (lg >> 1))
                               ? *(const int4*)&qb[wid][ks * 16 + lg * 4]
                               : zero4);
        bf16x8 k0f = bcast8(*(const int4*)(K0 + ks * 32 + lg * 8));
        bf16x8 k1f = bcast8(*(const int4*)(K1 + ks * 32 + lg * 8));
        accS[0] = __builtin_amdgcn_mfma_f32_16x16x32_bf16(k0f, qf, accS[0], 0, 0, 0);
        accS[1] = __builtin_amdgcn_mfma_f32_16x16x32_bf16(k1f, qf, accS[1], 0, 0, 0);
    }
    // enc.g: scores[m,h] += enc[m,:64] @ g[:64,h]
    #pragma unroll
    for (int ks = 0; ks < 2; ks++) {
        int4 gi = zero4;
        if (l15 < 8) {
            int2 ga = *(const int2*)&gbp[wid][l15][ks * 16 + lg * 4];
            int2 gbq = *(const int2*)&gbp[wid][l15][ks * 16 + lg * 4 + 2];
            gi.x = ga.x; gi.y = ga.y; gi.z = gbq.x; gi.w = gbq.y;
        }
        bf16x8 gf = bcast8(gi);
        bf16x8 e0 = *(const bf16x8*)&enc[wid][l15][ks * 32 + lg * 8];
        bf16x8 e1 = *(const bf16x8*)&enc[wid][l15 + 16][ks * 32 + lg * 8];
        accS[0] = __builtin_amdgcn_mfma_f32_16x16x32_bf16(e0, gf, accS[0], 0, 0, 0);
        accS[1] = __builtin_amdgcn_mfma_f32_16x16x32_bf16(e1, gf, accS[1], 0, 0, 0);
    }

    // ---- finalize + softmax (lane holds scores[m=mt*16+lg*4+j][h=l15]) ----
    float cbv = (l15 < 8) ? cb_[wid][l15] : 0.f;
    float sc[2][4];
    #pragma unroll
    for (int mt = 0; mt < 2; mt++) {
        #pragma unroll
        for (int j = 0; j < 4; j++) {
            int mr = mt * 16 + lg * 4 + j;
            float tmm = times[n * 32 + mr];
            float v = 0.25f * (accS[mt][j] + cbv);
            sc[mt][j] = (tmm <= t0) ? v : -1e9f;
        }
    }
    float mx = sc[0][0];
    #pragma unroll
    for (int mt = 0; mt < 2; mt++)
        #pragma unroll
        for (int j = 0; j < 4; j++) mx = fmaxf(mx, sc[mt][j]);
    mx = fmaxf(mx, __shfl_xor(mx, 16));
    mx = fmaxf(mx, __shfl_xor(mx, 32));
    float p[2][4];
    float s = 0.f;
    #pragma unroll
    for (int mt = 0; mt < 2; mt++)
        #pragma unroll
        for (int j = 0; j < 4; j++) { p[mt][j] = __expf(sc[mt][j] - mx); s += p[mt][j]; }
    s += __shfl_xor(s, 16);
    s += __shfl_xor(s, 32);
    float inv = 1.0f / s;
    if (l15 < 8) {
        #pragma unroll
        for (int mt = 0; mt < 2; mt++)
            #pragma unroll
            for (int j = 0; j < 4; j++)
                pbuf[wid][l15][mt * 16 + lg * 4 + j] = p[mt][j] * inv;
    }

    // ================= ewp = P^T @ enc via MFMA (K=32, one step) ==========
    {
        int hh = l15 & 7;
        float pa[8];
        #pragma unroll
        for (int j = 0; j < 8; j++) pa[j] = pbuf[wid][hh][8 * lg + j];
        int4 ai;
        ai.x = pk2(pa[0], pa[1]); ai.y = pk2(pa[2], pa[3]);
        ai.z = pk2(pa[4], pa[5]); ai.w = pk2(pa[6], pa[7]);
        bf16x8 af = bcast8(ai);
        #pragma unroll
        for (int nt = 0; nt < 4; nt++) {
            int col = nt * 16 + l15;
            int4 bi;
            bi.x = (u32)enc[wid][8 * lg + 0][col] | ((u32)enc[wid][8 * lg + 1][col] << 16);
            bi.y = (u32)enc[wid][8 * lg + 2][col] | ((u32)enc[wid][8 * lg + 3][col] << 16);
            bi.z = (u32)enc[wid][8 * lg + 4][col] | ((u32)enc[wid][8 * lg + 5][col] << 16);
            bi.w = (u32)enc[wid][8 * lg + 6][col] | ((u32)enc[wid][8 * lg + 7][col] << 16);
            bf16x8 bfr = bcast8(bi);
            f32x4 ce = (f32x4){0.f, 0.f, 0.f, 0.f};
            ce = __builtin_amdgcn_mfma_f32_16x16x32_bf16(af, bfr, ce, 0, 0, 0);
            if (lg < 2) {
                #pragma unroll
                for (int j = 0; j < 4; j++)
                    ewp[wid][4 * lg + j][col] = f2b(ce[j]);
            }
        }
    }

    // ---- V aggregation (VALU); lane owns cols (2*lane, 2*lane+1) ----
    int myh = lane >> 3;
    float av0 = 0.f, av1 = 0.f;
    #pragma unroll
    for (int mm = 0; mm < 32; mm++) {
        float a = pbuf[wid][myh][mm];
        av0 += a * bfl(vpre[mm]);
        av1 += a * bfh(vpre[mm]);
    }
    // ---- time-value term: ewb[myh] @ Wtv columns ----
    float ht0 = 0.f, ht1 = 0.f;
    #pragma unroll 8
    for (int kp = 0; kp < 32; kp++) {
        u32 ew = *(const u32*)&ewp[wid][myh][2 * kp];
        int2 wv = *(const int2*)&Wtvp[kp * 128 + 2 * lane];
        ht0 = dot2b(ew, (u32)wv.x, ht0);
        ht1 = dot2b(ew, (u32)wv.y, ht1);
    }
    float2 bt2 = *(const float2*)&btv[2 * lane];
    float2 o;
    o.x = anyv ? (av0 + ht0 + bt2.x) : 0.0f;
    o.y = anyv ? (av1 + ht1 + bt2.y) : 0.0f;
    *(float2*)&hbuf[(size_t)n * 128 + 2 * lane] = o;
}

// ---------------------------------------------------------------------------
extern "C" void kernel_launch(void* const* d_in, const int* in_sizes, int n_in,
                              void* d_out, int out_size, void* d_ws, size_t ws_size,
                              hipStream_t stream)
{
    const float* x        = (const float*)d_in[0];
    const int*   neighbors= (const int*)  d_in[1];
    const float* times    = (const float*)d_in[2];
    const float* t        = (const float*)d_in[3];
    const float* Wk  = (const float*)d_in[4];
    const float* bk  = (const float*)d_in[5];
    const float* Wq  = (const float*)d_in[6];
    const float* bq  = (const float*)d_in[7];
    const float* Wv  = (const float*)d_in[8];
    const float* bv  = (const float*)d_in[9];
    const float* w0  = (const float*)d_in[10];
    const float* b0  = (const float*)d_in[11];
    const float* Wt  = (const float*)d_in[12];
    const float* Bt  = (const float*)d_in[13];
    const float* Wtk = (const float*)d_in[14];
    const float* btk = (const float*)d_in[15];
    const float* Wtq = (const float*)d_in[16];
    const float* btq = (const float*)d_in[17];
    const float* Wtv = (const float*)d_in[18];
    const float* btv = (const float*)d_in[19];
    const float* W1  = (const float*)d_in[20];
    const float* b1  = (const float*)d_in[21];
    const float* W2  = (const float*)d_in[22];
    const float* b2  = (const float*)d_in[23];

    float* ws = (float*)d_ws;
    const size_t NF = (size_t)NNODES * 128;
    float* Ptab  = ws;                                   // NF f32
    float* hbuf  = Ptab + NF;                            // NF f32
    float* Utab  = hbuf + NF;                            // NF f32
    u16*   Kb    = (u16*)(Utab + NF);                    // NF bf16
    u16*   Qb    = Kb + NF;                              // NF bf16
    u16*   Vb    = Qb + NF;                              // NF bf16
    u16*   Gb    = Vb + NF;                              // N*512 bf16
    float* qbias = (float*)(Gb + (size_t)NNODES * 512);  // 128 f32
    u16*   Wts   = (u16*)(qbias + 128);                  // 6*16384 bf16
    u16*   WGt   = Wts + 6 * 16384;                      // 65536 bf16
    float* gb    = (float*)(WGt + 65536);                // 512 f32
    u32*   Wtvp  = (u32*)(gb + 512);                     // 4096 u32

    setup_all<<<107, 256, 0, stream>>>(Wk, Wq, Wv, W1, W2,
                                       t, bq, btq, Wtq, w0, b0, Wt, Bt,
                                       Wtk, Wtv,
                                       Wts, qbias, gb, Wtvp, WGt);

    gemm8m<<<dim3(NNODES / 128, 8), 256, 0, stream>>>(
        x, Wts, WGt, bk, qbias, bv, b1, gb, Kb, Qb, Vb, Ptab, Gb);

    attn_kernel<<<NNODES / 4, 256, 0, stream>>>(neighbors, times, t,
                                                Kb, Qb, Vb, Gb,
                                                btk, Wtvp, btv, w0, b0, Wt, Bt,
                                                hbuf);

    gemm_m<<<NNODES / 128, 256, 0, stream>>>(hbuf, Wts + 4 * 16384, nullptr,
                                             Ptab, Utab, 1);
    gemm_m<<<NNODES / 128, 256, 0, stream>>>(Utab, Wts + 5 * 16384, b2,
                                             nullptr, (float*)d_out, 0);
}

// Round 8
// 109.986 us; speedup vs baseline: 1.5035x; 1.1072x over previous
//
#include <hip/hip_runtime.h>
#include <hip/hip_bf16.h>

#define NNODES 16384

typedef unsigned short u16;
typedef unsigned int   u32;
typedef __attribute__((ext_vector_type(8))) short bf16x8;
typedef __attribute__((ext_vector_type(4))) float f32x4;

__device__ __forceinline__ float bfl(u32 u) { return __uint_as_float(u << 16); }
__device__ __forceinline__ float bfh(u32 u) { return __uint_as_float(u & 0xffff0000u); }
__device__ __forceinline__ u16 f2b(float f) {
    u32 u = __float_as_uint(f);
    return (u16)((u + 0x7fffu + ((u >> 16) & 1u)) >> 16);
}
__device__ __forceinline__ u32 pk2(float a, float b) {
    return (u32)f2b(a) | ((u32)f2b(b) << 16);
}
__device__ __forceinline__ bf16x8 bcast8(int4 v) {
    return __builtin_bit_cast(bf16x8, v);
}

#if defined(__has_builtin)
#if __has_builtin(__builtin_amdgcn_fdot2_f32_bf16)
#define HAVE_DOT2 1
#endif
#endif
#ifndef HAVE_DOT2
#define HAVE_DOT2 0
#endif

#if HAVE_DOT2
typedef __attribute__((ext_vector_type(2))) __bf16 bf16x2;
__device__ __forceinline__ float dot2b(u32 a, u32 b, float c) {
    return __builtin_amdgcn_fdot2_f32_bf16(__builtin_bit_cast(bf16x2, a),
                                           __builtin_bit_cast(bf16x2, b), c, false);
}
#else
__device__ __forceinline__ float dot2b(u32 a, u32 b, float c) {
    return c + bfl(a) * bfl(b) + bfh(a) * bfh(b);
}
#endif

// ---------------------------------------------------------------------------
// setup_all: one wide kernel, 107 blocks. (unchanged)
// ---------------------------------------------------------------------------
__global__ __launch_bounds__(256) void setup_all(
    const float* __restrict__ Wk, const float* __restrict__ Wq,
    const float* __restrict__ Wv, const float* __restrict__ W1,
    const float* __restrict__ W2,
    const float* __restrict__ t,  const float* __restrict__ bq,
    const float* __restrict__ btq,const float* __restrict__ Wtq,
    const float* __restrict__ w0, const float* __restrict__ b0,
    const float* __restrict__ Wt, const float* __restrict__ Bt,
    const float* __restrict__ Wtk,const float* __restrict__ Wtv,
    u16* __restrict__ Wts, float* __restrict__ qbias,
    float* __restrict__ gb, u32* __restrict__ Wtvp, u16* __restrict__ WGt)
{
    __shared__ float sb[128 * 17 + 64 * 17];
    int b = blockIdx.x, tt = threadIdx.x;

    if (b < 96) {
        int mat = b >> 4, tile = b & 15;
        const float* src = (mat == 0) ? Wk : (mat == 1) ? Wq : (mat == 2) ? Wv
                         : (mat == 3) ? W1 : (mat == 4) ? (W1 + 128 * 128) : W2;
        u16* dst = Wts + (size_t)mat * 16384;
        #pragma unroll
        for (int i = 0; i < 4; i++) {
            int o = i * 256 + tt;
            int cl = o >> 7, k = o & 127;
            int c = tile * 8 + cl;
            dst[c * 128 + k] = f2b(src[k * 128 + c]);
        }
    } else if (b == 96 || b == 97) {
        float tv = t[0];
        if (tt < 64)
            sb[tt] = (tt == 0) ? (w0[0] * tv + b0[0])
                               : __sinf(tv * Wt[tt - 1] + Bt[tt - 1]);
        __syncthreads();
        if (tt < 128) {
            float s = bq[tt] + btq[tt];
            for (int k = 0; k < 64; k++)
                s += sb[k] * Wtq[k * 128 + tt];
            sb[64 + tt] = s;
            if (b == 96) qbias[tt] = s;
        }
        __syncthreads();
        if (b == 97) {
            #pragma unroll
            for (int r = 0; r < 2; r++) {
                int hj = tt + r * 256;
                int h = hj >> 6, j = hj & 63;
                float s = 0.f;
                #pragma unroll
                for (int d = 0; d < 16; d++)
                    s += sb[64 + h * 16 + d] * Wtk[(size_t)j * 128 + h * 16 + d];
                gb[hj] = s;
            }
        }
    } else if (b == 98) {
        #pragma unroll
        for (int i = 0; i < 16; i++) {
            int idx = i * 256 + tt;
            int kp = idx >> 7, c = idx & 127;
            Wtvp[idx] = pk2(Wtv[(size_t)(2 * kp) * 128 + c],
                            Wtv[(size_t)(2 * kp + 1) * 128 + c]);
        }
    } else {
        int h = b - 99;
        float* WqL  = sb;
        float* WtkL = sb + 128 * 17;
        #pragma unroll
        for (int i = 0; i < 8; i++) {
            int o = i * 256 + tt;
            int k = o >> 4, d = o & 15;
            WqL[k * 17 + d] = Wq[(size_t)k * 128 + h * 16 + d];
        }
        #pragma unroll
        for (int i = 0; i < 4; i++) {
            int o = i * 256 + tt;
            int j = o >> 4, d = o & 15;
            WtkL[j * 17 + d] = Wtk[(size_t)j * 128 + h * 16 + d];
        }
        __syncthreads();
        int j = tt >> 2, kb = (tt & 3) * 32;
        float wk[16];
        #pragma unroll
        for (int d = 0; d < 16; d++) wk[d] = WtkL[j * 17 + d];
        u32 out[16];
        #pragma unroll
        for (int kk2 = 0; kk2 < 16; kk2++) {
            int k = kb + 2 * kk2;
            float s0 = 0.f, s1 = 0.f;
            #pragma unroll
            for (int d = 0; d < 16; d++) {
                s0 += WqL[k * 17 + d] * wk[d];
                s1 += WqL[(k + 1) * 17 + d] * wk[d];
            }
            out[kk2] = pk2(s0, s1);
        }
        int4* dst = (int4*)(WGt + (size_t)(h * 64 + j) * 128 + kb);
        const int4* srcv = (const int4*)out;
        #pragma unroll
        for (int i = 0; i < 4; i++) dst[i] = srcv[i];
    }
}

// ---------------------------------------------------------------------------
// gemm8m2: fused 8-matrix MFMA GEMM over x, 2 mats per block (x staged once).
// blockIdx.y = pair in [0,4): half 0 -> mat=pair (K/Q/V/P), half 1 -> mat=pair+4 (G tile)
// All outputs bf16.
// ---------------------------------------------------------------------------
__global__ __launch_bounds__(256) void gemm8m2(
    const float* __restrict__ x, const u16* __restrict__ Wts,
    const u16* __restrict__ WGt,
    const float* __restrict__ bk, const float* __restrict__ qbias,
    const float* __restrict__ bv, const float* __restrict__ b1,
    const float* __restrict__ gb,
    u16* __restrict__ Kb, u16* __restrict__ Qb,
    u16* __restrict__ Vb, u16* __restrict__ Pb, u16* __restrict__ Gb)
{
    __shared__ u16 As[128 * 128];
    __shared__ u16 Ws[128 * 128];
    int t = threadIdx.x;
    int rb = blockIdx.x * 128;
    int pair = blockIdx.y;

    // stage A (x tile, f32 -> bf16, swizzled) once
    u32* As32 = (u32*)As;
    u32* Ws32 = (u32*)Ws;
    const float2* Ap = (const float2*)(x + (size_t)rb * 128);
    #pragma unroll
    for (int i = 0; i < 32; i++) {
        int idx2 = i * 256 + t;
        int r = idx2 >> 6, k2 = idx2 & 63;
        float2 v = Ap[idx2];
        As32[(r * 64 + k2) ^ ((r & 7) << 2)] = pk2(v.x, v.y);
    }

    int wid = t >> 6, lane = t & 63;
    int l15 = lane & 15, lg = lane >> 4;
    int mb = wid * 32;
    int xo = (l15 & 7) << 3;

    #pragma unroll
    for (int half = 0; half < 2; half++) {
        int mat = pair + half * 4;
        const u16* Wt = (mat < 4) ? (Wts + (size_t)mat * 16384)
                                  : (WGt + (size_t)(mat - 4) * 16384);
        const float* bias = (mat == 0) ? bk : (mat == 1) ? qbias
                          : (mat == 2) ? bv : (mat == 3) ? b1
                          : (gb + (mat - 4) * 128);
        const u32* Wp = (const u32*)Wt;
        #pragma unroll
        for (int i = 0; i < 32; i++) {
            int idx2 = i * 256 + t;
            int c = idx2 >> 6, k2 = idx2 & 63;
            Ws32[(c * 64 + k2) ^ ((c & 7) << 2)] = Wp[idx2];
        }
        __syncthreads();

        f32x4 acc[2][8];
        #pragma unroll
        for (int mi = 0; mi < 2; mi++)
            #pragma unroll
            for (int nt = 0; nt < 8; nt++)
                acc[mi][nt] = (f32x4){0.f, 0.f, 0.f, 0.f};

        #pragma unroll
        for (int ks = 0; ks < 4; ks++) {
            int kq = ks * 32 + lg * 8;
            bf16x8 a0 = *(bf16x8*)&As[((mb + l15) * 128 + kq) ^ xo];
            bf16x8 a1 = *(bf16x8*)&As[((mb + 16 + l15) * 128 + kq) ^ xo];
            #pragma unroll
            for (int nt = 0; nt < 8; nt++) {
                bf16x8 b = *(bf16x8*)&Ws[((nt * 16 + l15) * 128 + kq) ^ xo];
                acc[0][nt] = __builtin_amdgcn_mfma_f32_16x16x32_bf16(a0, b, acc[0][nt], 0, 0, 0);
                acc[1][nt] = __builtin_amdgcn_mfma_f32_16x16x32_bf16(a1, b, acc[1][nt], 0, 0, 0);
            }
        }

        u16* dst = (mat == 0) ? Kb : (mat == 1) ? Qb : (mat == 2) ? Vb
                 : (mat == 3) ? Pb : Gb;
        #pragma unroll
        for (int mi = 0; mi < 2; mi++) {
            #pragma unroll
            for (int nt = 0; nt < 8; nt++) {
                int c = nt * 16 + l15;
                float bvv = bias[c];
                #pragma unroll
                for (int j = 0; j < 4; j++) {
                    size_t row = rb + mb + mi * 16 + lg * 4 + j;
                    float v = acc[mi][nt][j] + bvv;
                    if (mat < 4) dst[row * 128 + c] = f2b(v);
                    else         dst[row * 512 + (size_t)(mat - 4) * 128 + c] = f2b(v);
                }
            }
        }
        __syncthreads();   // all Ws reads done before next-half overwrite
    }
}

// ---------------------------------------------------------------------------
// mlp_fused: out = relu(Hb@W1b + Pb) @ W2 + b2, 64-row tiles (256 blocks).
// U kept on-chip: written bf16 back into As with the same XOR swizzle.
// ---------------------------------------------------------------------------
__global__ __launch_bounds__(256) void mlp_fused(
    const u16* __restrict__ Hb, const u16* __restrict__ Wts,
    const u16* __restrict__ Pb, const float* __restrict__ b2,
    float* __restrict__ out)
{
    __shared__ u16 As[64 * 128];     // 16 KB
    __shared__ u16 Ws[128 * 128];    // 32 KB
    int t = threadIdx.x;
    int rb = blockIdx.x * 64;
    u32* As32 = (u32*)As;
    u32* Ws32 = (u32*)Ws;

    // stage A (Hb bf16 tile, swizzled)
    const u32* Hp = (const u32*)(Hb + (size_t)rb * 128);
    #pragma unroll
    for (int i = 0; i < 16; i++) {
        int idx2 = i * 256 + t;
        int r = idx2 >> 6, k2 = idx2 & 63;
        As32[(r * 64 + k2) ^ ((r & 7) << 2)] = Hp[idx2];
    }
    // stage Ws = W1b
    {
        const u32* Wp = (const u32*)(Wts + 4 * 16384);
        #pragma unroll
        for (int i = 0; i < 32; i++) {
            int idx2 = i * 256 + t;
            int c = idx2 >> 6, k2 = idx2 & 63;
            Ws32[(c * 64 + k2) ^ ((c & 7) << 2)] = Wp[idx2];
        }
    }
    __syncthreads();

    int wid = t >> 6, lane = t & 63;
    int l15 = lane & 15, lg = lane >> 4;
    int mb = wid * 16;
    int xo = (l15 & 7) << 3;

    f32x4 acc[8];
    #pragma unroll
    for (int nt = 0; nt < 8; nt++) acc[nt] = (f32x4){0.f, 0.f, 0.f, 0.f};
    #pragma unroll
    for (int ks = 0; ks < 4; ks++) {
        int kq = ks * 32 + lg * 8;
        bf16x8 a0 = *(bf16x8*)&As[((mb + l15) * 128 + kq) ^ xo];
        #pragma unroll
        for (int nt = 0; nt < 8; nt++) {
            bf16x8 b = *(bf16x8*)&Ws[((nt * 16 + l15) * 128 + kq) ^ xo];
            acc[nt] = __builtin_amdgcn_mfma_f32_16x16x32_bf16(a0, b, acc[nt], 0, 0, 0);
        }
    }
    __syncthreads();   // all As/Ws reads of pass 1 done

    // U = relu(acc + Pb) -> bf16 back into As (swizzled); each wave owns its rows
    #pragma unroll
    for (int nt = 0; nt < 8; nt++) {
        int c = nt * 16 + l15;
        #pragma unroll
        for (int j = 0; j < 4; j++) {
            int row = mb + lg * 4 + j;
            float pv = bfl((u32)Pb[(size_t)(rb + row) * 128 + c]);
            float v = fmaxf(acc[nt][j] + pv, 0.f);
            As[(row * 128 + c) ^ ((row & 7) << 3)] = f2b(v);
        }
    }
    // stage Ws = W2
    {
        const u32* Wp = (const u32*)(Wts + 5 * 16384);
        #pragma unroll
        for (int i = 0; i < 32; i++) {
            int idx2 = i * 256 + t;
            int c = idx2 >> 6, k2 = idx2 & 63;
            Ws32[(c * 64 + k2) ^ ((c & 7) << 2)] = Wp[idx2];
        }
    }
    __syncthreads();

    #pragma unroll
    for (int nt = 0; nt < 8; nt++) acc[nt] = (f32x4){0.f, 0.f, 0.f, 0.f};
    #pragma unroll
    for (int ks = 0; ks < 4; ks++) {
        int kq = ks * 32 + lg * 8;
        bf16x8 a0 = *(bf16x8*)&As[((mb + l15) * 128 + kq) ^ xo];
        #pragma unroll
        for (int nt = 0; nt < 8; nt++) {
            bf16x8 b = *(bf16x8*)&Ws[((nt * 16 + l15) * 128 + kq) ^ xo];
            acc[nt] = __builtin_amdgcn_mfma_f32_16x16x32_bf16(a0, b, acc[nt], 0, 0, 0);
        }
    }
    #pragma unroll
    for (int nt = 0; nt < 8; nt++) {
        int c = nt * 16 + l15;
        float bvv = b2[c];
        #pragma unroll
        for (int j = 0; j < 4; j++) {
            size_t row = rb + mb + lg * 4 + j;
            out[row * 128 + c] = acc[nt][j] + bvv;
        }
    }
}

// ---------------------------------------------------------------------------
// Attention: one wave per node, 4 waves/block, wave-private LDS, no barriers.
// Scores (QK + enc.g) and ewp (P^T @ enc) on MFMA; value path on VALU.
// LDS 32640 B/block -> 5 blocks/CU.
// ---------------------------------------------------------------------------
__global__ __launch_bounds__(256, 5) void attn_kernel(
    const int*   __restrict__ neighbors, const float* __restrict__ times,
    const float* __restrict__ tptr,
    const u16* __restrict__ Kb, const u16* __restrict__ Qb,
    const u16* __restrict__ Vb, const u16* __restrict__ Gb,
    const float* __restrict__ btk,  const u32* __restrict__ Wtvp,
    const float* __restrict__ btv,
    const float* __restrict__ w0,   const float* __restrict__ b0,
    const float* __restrict__ Wt,   const float* __restrict__ Bt,
    u16* __restrict__ Hb)
{
    __shared__ u16   enc[4][32][72];
    __shared__ u32   gbp[4][8][32];
    __shared__ u32   qb[4][64];
    __shared__ float pbuf[4][8][33];
    __shared__ u16   ewp[4][8][66];
    __shared__ int   nbb[4][32];
    __shared__ float cb_[4][8];

    int t = threadIdx.x;
    int wid = t >> 6, lane = t & 63;
    int n = blockIdx.x * 4 + wid;
    float t0 = tptr[0];
    int l15 = lane & 15, lg = lane >> 4;

    qb[wid][lane] = ((const u32*)Qb)[(size_t)n * 64 + lane];
    {
        int4 g4 = *(const int4*)((const u32*)Gb + (size_t)n * 256 + 4 * lane);
        const u32* gw = (const u32*)&g4;
        #pragma unroll
        for (int i = 0; i < 4; i++) {
            int q4 = 4 * lane + i;
            gbp[wid][q4 >> 5][q4 & 31] = gw[i];
        }
    }

    int m = lane & 31, h2 = lane >> 5;
    if (lane < 32) nbb[wid][lane] = neighbors[n * 32 + lane];
    float tm = times[n * 32 + m];
    bool valid = (tm <= t0);
    unsigned long long bal = __ballot(valid);
    bool anyv = (bal != 0ull);

    // ---- V preload ----
    u32 vpre[32];
    #pragma unroll
    for (int mm = 0; mm < 32; mm++) {
        int nbm = nbb[wid][mm];
        vpre[mm] = *(const u32*)(Vb + (size_t)nbm * 128 + 2 * lane);
    }

    // ---- time encoding ----
    float W0 = w0[0], B0 = b0[0];
    int kbase = 32 * h2;
    #pragma unroll
    for (int i = 0; i < 16; i++) {
        int k0 = kbase + 2 * i;
        float v0 = (k0 == 0) ? (W0 * tm + B0) : __sinf(tm * Wt[k0 - 1] + Bt[k0 - 1]);
        float v1 = __sinf(tm * Wt[k0] + Bt[k0]);
        *(u32*)&enc[wid][m][k0] = pk2(v0, v1);
    }

    // cb_[h] = q_h . btk_h
    if (lane < 8) {
        float s = 0.f;
        #pragma unroll
        for (int j = 0; j < 8; j++) {
            u32 qp = qb[wid][lane * 8 + j];
            s += bfl(qp) * btk[lane * 16 + 2 * j] + bfh(qp) * btk[lane * 16 + 2 * j + 1];
        }
        cb_[wid][lane] = s;
    }

    // ================= scores via MFMA =================
    f32x4 accS[2];
    accS[0] = (f32x4){0.f, 0.f, 0.f, 0.f};
    accS[1] = (f32x4){0.f, 0.f, 0.f, 0.f};

    int nb0 = nbb[wid][l15];
    int nb1 = nbb[wid][l15 + 16];
    const u16* K0 = Kb + (size_t)nb0 * 128;
    const u16* K1 = Kb + (size_t)nb1 * 128;
    const int4 zero4 = {0, 0, 0, 0};
    #pragma unroll
    for (int ks = 0; ks < 4; ks++) {
        bf16x8 qf = bcast8((l15 == ks * 2 + (lg >> 1))
                               ? *(const int4*)&qb[wid][ks * 16 + lg * 4]
                               : zero4);
        bf16x8 k0f = bcast8(*(const int4*)(K0 + ks * 32 + lg * 8));
        bf16x8 k1f = bcast8(*(const int4*)(K1 + ks * 32 + lg * 8));
        accS[0] = __builtin_amdgcn_mfma_f32_16x16x32_bf16(k0f, qf, accS[0], 0, 0, 0);
        accS[1] = __builtin_amdgcn_mfma_f32_16x16x32_bf16(k1f, qf, accS[1], 0, 0, 0);
    }
    #pragma unroll
    for (int ks = 0; ks < 2; ks++) {
        int4 gi = zero4;
        if (l15 < 8) {
            int2 ga = *(const int2*)&gbp[wid][l15][ks * 16 + lg * 4];
            int2 gbq = *(const int2*)&gbp[wid][l15][ks * 16 + lg * 4 + 2];
            gi.x = ga.x; gi.y = ga.y; gi.z = gbq.x; gi.w = gbq.y;
        }
        bf16x8 gf = bcast8(gi);
        bf16x8 e0 = *(const bf16x8*)&enc[wid][l15][ks * 32 + lg * 8];
        bf16x8 e1 = *(const bf16x8*)&enc[wid][l15 + 16][ks * 32 + lg * 8];
        accS[0] = __builtin_amdgcn_mfma_f32_16x16x32_bf16(e0, gf, accS[0], 0, 0, 0);
        accS[1] = __builtin_amdgcn_mfma_f32_16x16x32_bf16(e1, gf, accS[1], 0, 0, 0);
    }

    // ---- finalize + softmax (mask from ballot; no times re-read) ----
    float cbv = (l15 < 8) ? cb_[wid][l15] : 0.f;
    float sc[2][4];
    #pragma unroll
    for (int mt = 0; mt < 2; mt++) {
        #pragma unroll
        for (int j = 0; j < 4; j++) {
            int mr = mt * 16 + lg * 4 + j;
            float v = 0.25f * (accS[mt][j] + cbv);
            sc[mt][j] = ((bal >> mr) & 1ull) ? v : -1e9f;
        }
    }
    float mx = sc[0][0];
    #pragma unroll
    for (int mt = 0; mt < 2; mt++)
        #pragma unroll
        for (int j = 0; j < 4; j++) mx = fmaxf(mx, sc[mt][j]);
    mx = fmaxf(mx, __shfl_xor(mx, 16));
    mx = fmaxf(mx, __shfl_xor(mx, 32));
    float p[2][4];
    float s = 0.f;
    #pragma unroll
    for (int mt = 0; mt < 2; mt++)
        #pragma unroll
        for (int j = 0; j < 4; j++) { p[mt][j] = __expf(sc[mt][j] - mx); s += p[mt][j]; }
    s += __shfl_xor(s, 16);
    s += __shfl_xor(s, 32);
    float inv = 1.0f / s;
    if (l15 < 8) {
        #pragma unroll
        for (int mt = 0; mt < 2; mt++)
            #pragma unroll
            for (int j = 0; j < 4; j++)
                pbuf[wid][l15][mt * 16 + lg * 4 + j] = p[mt][j] * inv;
    }

    // ================= ewp = P^T @ enc via MFMA =================
    {
        int hh = l15 & 7;
        float pa[8];
        #pragma unroll
        for (int j = 0; j < 8; j++) pa[j] = pbuf[wid][hh][8 * lg + j];
        int4 ai;
        ai.x = pk2(pa[0], pa[1]); ai.y = pk2(pa[2], pa[3]);
        ai.z = pk2(pa[4], pa[5]); ai.w = pk2(pa[6], pa[7]);
        bf16x8 af = bcast8(ai);
        #pragma unroll
        for (int nt = 0; nt < 4; nt++) {
            int col = nt * 16 + l15;
            int4 bi;
            bi.x = (u32)enc[wid][8 * lg + 0][col] | ((u32)enc[wid][8 * lg + 1][col] << 16);
            bi.y = (u32)enc[wid][8 * lg + 2][col] | ((u32)enc[wid][8 * lg + 3][col] << 16);
            bi.z = (u32)enc[wid][8 * lg + 4][col] | ((u32)enc[wid][8 * lg + 5][col] << 16);
            bi.w = (u32)enc[wid][8 * lg + 6][col] | ((u32)enc[wid][8 * lg + 7][col] << 16);
            bf16x8 bfr = bcast8(bi);
            f32x4 ce = (f32x4){0.f, 0.f, 0.f, 0.f};
            ce = __builtin_amdgcn_mfma_f32_16x16x32_bf16(af, bfr, ce, 0, 0, 0);
            if (lg < 2) {
                #pragma unroll
                for (int j = 0; j < 4; j++)
                    ewp[wid][4 * lg + j][col] = f2b(ce[j]);
            }
        }
    }

    // ---- V aggregation (VALU) ----
    int myh = lane >> 3;
    float av0 = 0.f, av1 = 0.f;
    #pragma unroll
    for (int mm = 0; mm < 32; mm++) {
        float a = pbuf[wid][myh][mm];
        av0 += a * bfl(vpre[mm]);
        av1 += a * bfh(vpre[mm]);
    }
    // ---- time-value term ----
    float ht0 = 0.f, ht1 = 0.f;
    #pragma unroll 8
    for (int kp = 0; kp < 32; kp++) {
        u32 ew = *(const u32*)&ewp[wid][myh][2 * kp];
        int2 wv = *(const int2*)&Wtvp[kp * 128 + 2 * lane];
        ht0 = dot2b(ew, (u32)wv.x, ht0);
        ht1 = dot2b(ew, (u32)wv.y, ht1);
    }
    float2 bt2 = *(const float2*)&btv[2 * lane];
    float ox = anyv ? (av0 + ht0 + bt2.x) : 0.0f;
    float oy = anyv ? (av1 + ht1 + bt2.y) : 0.0f;
    ((u32*)Hb)[(size_t)n * 64 + lane] = pk2(ox, oy);
}

// ---------------------------------------------------------------------------
extern "C" void kernel_launch(void* const* d_in, const int* in_sizes, int n_in,
                              void* d_out, int out_size, void* d_ws, size_t ws_size,
                              hipStream_t stream)
{
    const float* x        = (const float*)d_in[0];
    const int*   neighbors= (const int*)  d_in[1];
    const float* times    = (const float*)d_in[2];
    const float* t        = (const float*)d_in[3];
    const float* Wk  = (const float*)d_in[4];
    const float* bk  = (const float*)d_in[5];
    const float* Wq  = (const float*)d_in[6];
    const float* bq  = (const float*)d_in[7];
    const float* Wv  = (const float*)d_in[8];
    const float* bv  = (const float*)d_in[9];
    const float* w0  = (const float*)d_in[10];
    const float* b0  = (const float*)d_in[11];
    const float* Wt  = (const float*)d_in[12];
    const float* Bt  = (const float*)d_in[13];
    const float* Wtk = (const float*)d_in[14];
    const float* btk = (const float*)d_in[15];
    const float* Wtq = (const float*)d_in[16];
    const float* btq = (const float*)d_in[17];
    const float* Wtv = (const float*)d_in[18];
    const float* btv = (const float*)d_in[19];
    const float* W1  = (const float*)d_in[20];
    const float* b1  = (const float*)d_in[21];
    const float* W2  = (const float*)d_in[22];
    const float* b2  = (const float*)d_in[23];

    float* ws = (float*)d_ws;
    const size_t NF = (size_t)NNODES * 128;
    u16*   Kb    = (u16*)ws;                             // NF bf16
    u16*   Qb    = Kb + NF;                              // NF bf16
    u16*   Vb    = Qb + NF;                              // NF bf16
    u16*   Pb    = Vb + NF;                              // NF bf16
    u16*   Hb    = Pb + NF;                              // NF bf16
    u16*   Gb    = Hb + NF;                              // N*512 bf16
    float* qbias = (float*)(Gb + (size_t)NNODES * 512);  // 128 f32
    u16*   Wts   = (u16*)(qbias + 128);                  // 6*16384 bf16
    u16*   WGt   = Wts + 6 * 16384;                      // 65536 bf16
    float* gb    = (float*)(WGt + 65536);                // 512 f32
    u32*   Wtvp  = (u32*)(gb + 512);                     // 4096 u32

    setup_all<<<107, 256, 0, stream>>>(Wk, Wq, Wv, W1, W2,
                                       t, bq, btq, Wtq, w0, b0, Wt, Bt,
                                       Wtk, Wtv,
                                       Wts, qbias, gb, Wtvp, WGt);

    gemm8m2<<<dim3(NNODES / 128, 4), 256, 0, stream>>>(
        x, Wts, WGt, bk, qbias, bv, b1, gb, Kb, Qb, Vb, Pb, Gb);

    attn_kernel<<<NNODES / 4, 256, 0, stream>>>(neighbors, times, t,
                                                Kb, Qb, Vb, Gb,
                                                btk, Wtvp, btv, w0, b0, Wt, Bt,
                                                Hb);

    mlp_fused<<<NNODES / 64, 256, 0, stream>>>(Hb, Wts, Pb, b2,
                                               (float*)d_out);
}